// Round 7
// baseline (476.463 us; speedup 1.0000x reference)
//
#include <hip/hip_runtime.h>

typedef __bf16 bf16;
typedef __bf16 bf16x8 __attribute__((ext_vector_type(8)));
typedef __bf16 bf16x4 __attribute__((ext_vector_type(4)));
typedef float  f32x4  __attribute__((ext_vector_type(4)));

#define D_     1024
#define FFN_   4096
#define NH_    8
#define HD_    128
#define L_     2048
#define B_     2
#define ROWS_  4096           // B_*L_
#define PAIRS_ 16             // B_*NH_
#define KT_    64             // flash K-tile (keys)
#define PSTR   72             // Ps row stride (bf16): 144 B = 16B-aligned rows
#define ALPHA_  0.08838834764831845f   // 1/sqrt(128)
#define RSCALE_ 5.656854249492381f     // 0.5/ALPHA_

// async 16B global -> LDS (wave-uniform LDS base + lane*16 implicit)
__device__ __forceinline__ void async16(const bf16* g, bf16* l) {
    __builtin_amdgcn_global_load_lds(
        (const __attribute__((address_space(1))) unsigned int*)g,
        (__attribute__((address_space(3))) unsigned int*)l, 16, 0, 0);
}
__device__ __forceinline__ f32x4 MFMA(bf16x8 a, bf16x8 b, f32x4 c) {
    return __builtin_amdgcn_mfma_f32_16x16x32_bf16(a, b, c, 0, 0, 0);
}

// ---------------- elementwise fp32 -> bf16 ----------------
__global__ void cvt_bf16_kernel(const float* __restrict__ in, bf16* __restrict__ out) {
    long i = ((long)blockIdx.x * 256 + threadIdx.x) * 4;
    float4 v = *(const float4*)(in + i);
    bf16x4 o = {(bf16)v.x, (bf16)v.y, (bf16)v.z, (bf16)v.w};
    *(bf16x4*)(out + i) = o;
}

// ---------------- tiled transpose (TI -> bf16), batched over z ----------------
template<typename TI>
__global__ void transpose_to_bf16(const TI* __restrict__ in, bf16* __restrict__ out,
                                  int r, int c, long sIn, long sOut) {
    __shared__ bf16 t[32][33];
    long zi = (long)blockIdx.z * sIn;
    long zo = (long)blockIdx.z * sOut;
    int x0 = blockIdx.x * 32, y0 = blockIdx.y * 32;
    int tx = threadIdx.x & 31, ty = threadIdx.x >> 5;  // 32 x 8
#pragma unroll
    for (int i = 0; i < 4; i++)
        t[ty + i * 8][tx] = (bf16)in[zi + (long)(y0 + ty + i * 8) * c + x0 + tx];
    __syncthreads();
#pragma unroll
    for (int i = 0; i < 4; i++)
        out[zo + (long)(x0 + ty + i * 8) * r + y0 + tx] = t[tx][ty + i * 8];
}

// ---------------- tiny relevance projections ----------------
__global__ void rqk_kernel(const float* __restrict__ rh, const float* __restrict__ Wrq,
                           const float* __restrict__ Wrk, float* __restrict__ rq,
                           float* __restrict__ rk) {
    int t = blockIdx.x * 256 + threadIdx.x;
    float4 r = *(const float4*)(rh + (long)t * 4);
    float q[4], k[4];
#pragma unroll
    for (int c = 0; c < 4; c++) {
        q[c] = r.x * Wrq[c] + r.y * Wrq[4 + c] + r.z * Wrq[8 + c] + r.w * Wrq[12 + c];
        k[c] = r.x * Wrk[c] + r.y * Wrk[4 + c] + r.z * Wrk[8 + c] + r.w * Wrk[12 + c];
    }
    float4 qo = {q[0], q[1], q[2], q[3]};
    float4 ko = {k[0], k[1], k[2], k[3]};
    *(float4*)(rq + (long)t * 4) = qo;
    *(float4*)(rk + (long)t * 4) = ko;
}

// ---------------- m97-style MFMA GEMM (kept for Wo) ----------------
template<int BM, int EPI>
__launch_bounds__(256)
__global__ void gemm128(const bf16* __restrict__ A, const bf16* __restrict__ Bt,
                        void* __restrict__ Cv, const float* __restrict__ bias,
                        int M, int N, int K, int lda, int ldb,
                        long sA, long sB, long sC, float alpha) {
    constexpr int RF = (BM == 128) ? 4 : 2;
    __shared__ __align__(16) bf16 As[BM * 32];
    __shared__ __align__(16) bf16 Bs[128 * 32];
    const int tid  = threadIdx.x;
    const int wave = tid >> 6, lane = tid & 63;
    const int quad = lane >> 4, mr = lane & 15;
    const int bM = blockIdx.x * BM, bN = blockIdx.y * 128;
    A  += (long)blockIdx.z * sA;
    Bt += (long)blockIdx.z * sB;
    const int wr = (wave >> 1) * (BM / 2), wc = (wave & 1) * 64;

    f32x4 acc[RF][4];
#pragma unroll
    for (int r = 0; r < RF; r++)
#pragma unroll
        for (int c = 0; c < 4; c++) { f32x4 z = {0.f, 0.f, 0.f, 0.f}; acc[r][c] = z; }

    const int scol = (lane & 3) * 8;
    const bf16* Ag0; const bf16* Ag1 = nullptr;
    if (BM == 128) {
        const int srow = wave * 32 + (lane >> 2);
        Ag0 = A + (long)(bM + srow) * lda + scol;
        Ag1 = Ag0 + (long)16 * lda;
    } else {
        const int srow = wave * 16 + (lane >> 2);
        Ag0 = A + (long)(bM + srow) * lda + scol;
    }
    const int srowB = wave * 32 + (lane >> 2);
    const bf16* Bg0 = Bt + (long)(bN + srowB) * ldb + scol;
    const bf16* Bg1 = Bg0 + (long)16 * ldb;
    bf16* AsW = As + wave * (BM == 128 ? 1024 : 512);
    bf16* BsW = Bs + wave * 1024;

    for (int k0 = 0; k0 < K; k0 += 32) {
        if (BM == 128) { async16(Ag0, AsW); async16(Ag1, AsW + 512); Ag0 += 32; Ag1 += 32; }
        else           { async16(Ag0, AsW); Ag0 += 32; }
        async16(Bg0, BsW); async16(Bg1, BsW + 512);
        Bg0 += 32; Bg1 += 32;
        __syncthreads();
        bf16x8 af[RF], bfv[4];
#pragma unroll
        for (int r = 0; r < RF; r++)
            af[r] = *(const bf16x8*)(&As[(wr + r * 16 + mr) * 32 + quad * 8]);
#pragma unroll
        for (int c = 0; c < 4; c++)
            bfv[c] = *(const bf16x8*)(&Bs[(wc + c * 16 + mr) * 32 + quad * 8]);
#pragma unroll
        for (int r = 0; r < RF; r++)
#pragma unroll
            for (int c = 0; c < 4; c++)
                acc[r][c] = MFMA(af[r], bfv[c], acc[r][c]);
        __syncthreads();
    }

    const long zC = (long)blockIdx.z * sC;
    float bias_c[4];
    if (EPI & 1) {
#pragma unroll
        for (int c = 0; c < 4; c++) bias_c[c] = bias[bN + wc + c * 16 + mr];
    }
#pragma unroll
    for (int r = 0; r < RF; r++) {
#pragma unroll
        for (int c = 0; c < 4; c++) {
            const long col = bN + wc + c * 16 + mr;
#pragma unroll
            for (int i = 0; i < 4; i++) {
                const long row = bM + wr + r * 16 + quad * 4 + i;
                float v = acc[r][c][i] * alpha;
                if (EPI & 1) v += bias_c[c];
                if (EPI & 2) v = fmaxf(v, 0.f);
                if (EPI & 4) ((bf16*)Cv)[zC + row * (long)N + col] = (bf16)v;
                else         ((float*)Cv)[zC + row * (long)N + col] = v;
            }
        }
    }
}

// ---------------- 128x256-tile GEMM, 4 waves, ring-2 LDS (48 KB -> 2 blocks/CU) -----
// Rationale: gemm256 (128 KB LDS, 1 block/CU, 2 waves/SIMD) measured ~660 TF.
// Same per-wave work (acc[8][4], 32 MFMA/K-tile) but: grids >= 384-512 blocks ->
// 2 resident blocks/CU (cross-block TLP, the mechanism round-0 flash proved);
// ONE barrier per K-tile; issue-early staging (stage t+1 at top of iter t, the
// vmcnt(0) at the tile boundary waits on loads issued ~650 cycles earlier).
// Swizzle/fragment algebra identical to the verified gemm256.
template<int EPI>
__launch_bounds__(256)
__global__ void gemmA(const bf16* __restrict__ A, const bf16* __restrict__ Bt,
                      void* __restrict__ Cv, const float* __restrict__ bias,
                      int M, int N, int K, int lda, int ldb,
                      long sA, long sB, long sC, float alpha) {
    __shared__ __align__(16) bf16 As[2][128 * 32];   // 8 KB per slot
    __shared__ __align__(16) bf16 Bs[2][256 * 32];   // 16 KB per slot
    const int tid = threadIdx.x, wave = tid >> 6, lane = tid & 63;
    const int quad = lane >> 4, mr = lane & 15;
    const int bM = blockIdx.x * 128, bN = blockIdx.y * 256;
    (void)M;
    A  += (long)blockIdx.z * sA;
    Bt += (long)blockIdx.z * sB;

    // staging: thread covers row (tid>>2) [+64/128/192 on later issues], granule
    // pre-swizzled on the GLOBAL side: g = (tid&3) ^ ((row>>1)&3); (tid>>3)&3 works
    // for all issues since the row offsets (64,128,192) are 0 mod 8.
    const int srow = tid >> 2;
    const int sg   = (((tid & 3) ^ ((tid >> 3) & 3))) * 8;
    const bf16* Ag = A  + (long)(bM + srow) * lda + sg;
    const bf16* Bg = Bt + (long)(bN + srow) * ldb + sg;

    auto stage = [&](int slot, int t) {
        const bf16* a = Ag + t * 32;
        async16(a,                   &As[slot][wave * 512]);
        async16(a + (long)64 * lda,  &As[slot][2048 + wave * 512]);
        const bf16* bs = Bg + t * 32;
        async16(bs,                  &Bs[slot][wave * 512]);
        async16(bs + (long)64 * ldb, &Bs[slot][2048 + wave * 512]);
        async16(bs + (long)128 * ldb, &Bs[slot][4096 + wave * 512]);
        async16(bs + (long)192 * ldb, &Bs[slot][6144 + wave * 512]);
    };

    f32x4 acc[8][4];
#pragma unroll
    for (int f = 0; f < 8; f++)
#pragma unroll
        for (int n = 0; n < 4; n++) { f32x4 z = {0.f, 0.f, 0.f, 0.f}; acc[f][n] = z; }

    // ds_read swizzled granule (row&15 == mr for all fragment rows; 16-row and
    // 64-row offsets don't change (row>>1)&3)
    const int gsw = (quad ^ ((mr >> 1) & 3)) * 8;

    const int NT = K >> 5;
    // prologue: stage tile 0; only exposed drain
    stage(0, 0);
    asm volatile("s_waitcnt vmcnt(0)" ::: "memory");
    __builtin_amdgcn_s_barrier();

    for (int t = 0; t < NT; ++t) {
        const int slot = t & 1;
        // issue-early: next tile into the other slot (its previous tenant t-1 was
        // fully read before the barrier that ended iter t-1)
        if (t + 1 < NT) stage(slot ^ 1, t + 1);

        bf16x8 af[8], bfv[4];
#pragma unroll
        for (int f = 0; f < 8; f++)
            af[f] = *(const bf16x8*)(&As[slot][(f * 16 + mr) * 32 + gsw]);
#pragma unroll
        for (int n = 0; n < 4; n++)
            bfv[n] = *(const bf16x8*)(&Bs[slot][(wave * 64 + n * 16 + mr) * 32 + gsw]);
        asm volatile("s_waitcnt lgkmcnt(0)" ::: "memory");
        __builtin_amdgcn_sched_barrier(0);
        __builtin_amdgcn_s_setprio(1);
#pragma unroll
        for (int f = 0; f < 8; f++)
#pragma unroll
            for (int n = 0; n < 4; n++)
                acc[f][n] = MFMA(af[f], bfv[n], acc[f][n]);
        __builtin_amdgcn_s_setprio(0);
        // tile boundary: wait for tile t+1's loads (issued before this tile's
        // compute, ~650 cycles of ds_read+MFMA ago)
        if (t + 1 < NT) asm volatile("s_waitcnt vmcnt(0)" ::: "memory");
        __builtin_amdgcn_s_barrier();
    }

    const long zC = (long)blockIdx.z * sC;
    float bias_c[4];
    if (EPI & 1) {
#pragma unroll
        for (int n = 0; n < 4; n++) bias_c[n] = bias[bN + wave * 64 + n * 16 + mr];
    }
#pragma unroll
    for (int f = 0; f < 8; f++) {
#pragma unroll
        for (int n = 0; n < 4; n++) {
            const long col = bN + wave * 64 + n * 16 + mr;
#pragma unroll
            for (int i = 0; i < 4; i++) {
                const long row = bM + f * 16 + quad * 4 + i;
                float v = acc[f][n][i] * alpha;
                if (EPI & 1) v += bias_c[n];
                if (EPI & 2) v = fmaxf(v, 0.f);
                if (EPI & 4) ((bf16*)Cv)[zC + row * (long)N + col] = (bf16)v;
                else         ((float*)Cv)[zC + row * (long)N + col] = v;
            }
        }
    }
}

// ---------------- fused flash attention with relevance bias, K-split ----------------
// Round-4 proven body (4 waves, 128-row Q-tile, single-buffered 2-barrier loop,
// 51 KB LDS) + T1 bijective XCD chunking (FETCH 74->17 MB verified) + T5 setprio.
template<int SPLIT>
__launch_bounds__(256, 1)
__global__ void flash_attn(const bf16* __restrict__ qb, const bf16* __restrict__ kT,
                           const bf16* __restrict__ vT, const float* __restrict__ rq,
                           const float* __restrict__ rk, bf16* __restrict__ ctx,
                           float* __restrict__ opart, float* __restrict__ osum) {
    __shared__ __align__(16) bf16  Ksh[KT_ * HD_];   // [key][d], granule-swizzled
    __shared__ __align__(16) bf16  Vsh[HD_ * KT_];   // [d][key], granule-swizzled
    __shared__ __align__(16) float rks[4 * KT_];     // [r][key] fp32
    __shared__ __align__(16) bf16  Ps[4][32 * PSTR]; // per-wave P, 16B-aligned rows

    const int tid = threadIdx.x, wave = tid >> 6, lane = tid & 63;
    const int quad = lane >> 4, mr = lane & 15;
    // T1: bijective XCD chunking. grid (16,16,SPLIT) -> nwg = 256*SPLIT (div by 8).
    const int nwg = 256 * SPLIT;
    const int lid = blockIdx.x + (blockIdx.y << 4) + (blockIdx.z << 8);
    const int wid = (lid & 7) * (nwg >> 3) + (lid >> 3);
    const int ksp = wid >> 8;
    const int pair = (wid >> 4) & 15, b = pair >> 3;
    const int bQ = (wid & 15) * 128;
    const long PB = (long)pair * L_ * HD_;
    const bf16* Qg = qb + PB;
    const bf16* Kg = kT + PB;
    const bf16* Vg = vT + PB;
    const float* rkb = rk + (long)b * L_ * 4;

    // Q fragments in registers (A-layout): rows bQ + wave*32 + f*16 + mr
    bf16x8 Qf[2][4], Qe[2];
#pragma unroll
    for (int f = 0; f < 2; f++) {
#pragma unroll
        for (int t = 0; t < 4; t++)
            Qf[f][t] = *(const bf16x8*)(Qg + (long)(bQ + wave * 32 + f * 16 + mr) * HD_ + t * 32 + quad * 8);
        bf16x8 z = {};
        if (quad == 0) {
            float4 v = *(const float4*)(rq + ((long)b * L_ + bQ + wave * 32 + f * 16 + mr) * 4);
            z[0] = (bf16)(v.x * RSCALE_); z[1] = (bf16)(v.y * RSCALE_);
            z[2] = (bf16)(v.z * RSCALE_); z[3] = (bf16)(v.w * RSCALE_);
        }
        Qe[f] = z;
    }

    bf16x8 ones;
#pragma unroll
    for (int j = 0; j < 8; j++) ones[j] = (bf16)1.0f;

    f32x4 O[2][8], Os[2];
#pragma unroll
    for (int f = 0; f < 2; f++) {
#pragma unroll
        for (int c = 0; c < 8; c++) { f32x4 z = {0.f, 0.f, 0.f, 0.f}; O[f][c] = z; }
        f32x4 z = {0.f, 0.f, 0.f, 0.f}; Os[f] = z;
    }

    const int tile0 = ksp * ((L_ / KT_) / SPLIT);
    const int tile1 = tile0 + (L_ / KT_) / SPLIT;
    for (int kt = tile0; kt < tile1; kt++) {
        const int kt0 = kt * KT_;
        // ---- stage K/V/rk (single buffer) ----
#pragma unroll
        for (int it = 0; it < 4; it++) {
            int G = it * 256 + tid;
            int r1 = G >> 4, g1 = (G & 15) ^ (r1 & 15);
            async16(Kg + (long)(kt0 + r1) * HD_ + g1 * 8, &Ksh[(it * 256 + wave * 64) * 8]);
            int r2 = G >> 3, g2 = (G & 7) ^ (r2 & 7);
            async16(Vg + (long)r2 * L_ + kt0 + g2 * 8, &Vsh[(it * 256 + wave * 64) * 8]);
        }
        if (tid < 64) {
            int r3 = tid >> 4, g3 = tid & 15;
            async16((const bf16*)(rkb + (long)r3 * L_ + kt0 + g3 * 4), (bf16*)&rks[0]);
        }
        __syncthreads();   // drains vmcnt -> LDS valid for all waves

        bf16* PsW = Ps[wave];

        // ---- S = Q K^T (+ ext bias chunk), 4 col-blocks of 16 keys ----
        f32x4 sc[4][2];
        __builtin_amdgcn_s_setprio(1);
#pragma unroll
        for (int c = 0; c < 4; c++) {
            f32x4 s0 = {0.f, 0.f, 0.f, 0.f}, s1 = s0;
#pragma unroll
            for (int t = 0; t < 4; t++) {
                bf16x8 kf = *(const bf16x8*)(Ksh + (c * 16 + mr) * HD_ + (((t * 4 + quad) ^ mr) * 8));
                s0 = MFMA(Qf[0][t], kf, s0);
                s1 = MFMA(Qf[1][t], kf, s1);
            }
            bf16x8 ke = {};
            if (quad == 0) {
                ke[0] = (bf16)rks[0 * KT_ + c * 16 + mr];
                ke[1] = (bf16)rks[1 * KT_ + c * 16 + mr];
                ke[2] = (bf16)rks[2 * KT_ + c * 16 + mr];
                ke[3] = (bf16)rks[3 * KT_ + c * 16 + mr];
            }
            s0 = MFMA(Qe[0], ke, s0);
            s1 = MFMA(Qe[1], ke, s1);
            sc[c][0] = s0; sc[c][1] = s1;
        }
        __builtin_amdgcn_s_setprio(0);

        // ---- P = exp(ALPHA*S) straight to LDS (no max, no shuffles) ----
#pragma unroll
        for (int f = 0; f < 2; f++) {
#pragma unroll
            for (int i = 0; i < 4; i++) {
                const int prow = (f * 16 + quad * 4 + i) * PSTR;
                PsW[prow + 0 * 16 + mr] = (bf16)__expf(sc[0][f][i] * ALPHA_);
                PsW[prow + 1 * 16 + mr] = (bf16)__expf(sc[1][f][i] * ALPHA_);
                PsW[prow + 2 * 16 + mr] = (bf16)__expf(sc[2][f][i] * ALPHA_);
                PsW[prow + 3 * 16 + mr] = (bf16)__expf(sc[3][f][i] * ALPHA_);
            }
        }

        // ---- O += P @ V ; Os += P @ ones (row sums) ----
        __builtin_amdgcn_s_setprio(1);
#pragma unroll
        for (int t = 0; t < 2; t++) {
            bf16x8 pf0 = *(const bf16x8*)(PsW + (0 * 16 + mr) * PSTR + t * 32 + quad * 8);
            bf16x8 pf1 = *(const bf16x8*)(PsW + (1 * 16 + mr) * PSTR + t * 32 + quad * 8);
            Os[0] = MFMA(pf0, ones, Os[0]);
            Os[1] = MFMA(pf1, ones, Os[1]);
#pragma unroll
            for (int c2 = 0; c2 < 8; c2++) {
                bf16x8 vf = *(const bf16x8*)(Vsh + (c2 * 16 + mr) * KT_ + (((t * 4 + quad) ^ (mr & 7)) * 8));
                O[0][c2] = MFMA(pf0, vf, O[0][c2]);
                O[1][c2] = MFMA(pf1, vf, O[1][c2]);
            }
        }
        __builtin_amdgcn_s_setprio(0);
        __syncthreads();   // all waves done reading K/V before restage
    }

    // ---- epilogue ----
    if (SPLIT == 1) {
        bf16* Cg = ctx + PB;
#pragma unroll
        for (int f = 0; f < 2; f++)
#pragma unroll
            for (int i = 0; i < 4; i++) {
                const float inv = 1.f / Os[f][i];
                const long row = bQ + wave * 32 + f * 16 + quad * 4 + i;
#pragma unroll
                for (int c2 = 0; c2 < 8; c2++)
                    Cg[row * HD_ + c2 * 16 + mr] = (bf16)(O[f][c2][i] * inv);
            }
    } else {
        float* Og = opart + (long)ksp * ((long)PAIRS_ * L_ * HD_) + PB;
        float* Sg = osum + (long)ksp * (PAIRS_ * L_) + pair * L_;
#pragma unroll
        for (int f = 0; f < 2; f++)
#pragma unroll
            for (int i = 0; i < 4; i++) {
                const long row = bQ + wave * 32 + f * 16 + quad * 4 + i;
#pragma unroll
                for (int c2 = 0; c2 < 8; c2++)
                    Og[row * HD_ + c2 * 16 + mr] = O[f][c2][i];
                if (mr == 0) Sg[row] = Os[f][i];
            }
    }
}

// --------- combine KS flash partials: ctx = (sum O_z) / (sum s_z) ----------
template<int KS>
__global__ void flash_reduce(const float* __restrict__ op, const float* __restrict__ os,
                             bf16* __restrict__ ctx) {
    const long PLHD = (long)PAIRS_ * L_ * HD_;
    long e = ((long)blockIdx.x * 256 + threadIdx.x) * 4;
    long row = e >> 7;                       // / HD_
    float4 a = *(const float4*)(op + e);
    float s = os[row];
#pragma unroll
    for (int z = 1; z < KS; z++) {
        float4 p = *(const float4*)(op + (long)z * PLHD + e);
        a.x += p.x; a.y += p.y; a.z += p.z; a.w += p.w;
        s += os[(long)z * PAIRS_ * L_ + row];
    }
    float inv = 1.f / s;
    bf16x4 o = {(bf16)(a.x * inv), (bf16)(a.y * inv),
                (bf16)(a.z * inv), (bf16)(a.w * inv)};
    *(bf16x4*)(ctx + e) = o;
}

// ---------------- LN1: layernorm(x1 + x2) * g + be ; fp32 + bf16 out ----------------
__global__ void layernorm_res(const float* __restrict__ x1, const float* __restrict__ x2,
                              const float* __restrict__ g, const float* __restrict__ be,
                              float* __restrict__ outf, bf16* __restrict__ outb) {
    const int row = blockIdx.x, tid = threadIdx.x;
    const long base = (long)row * D_ + tid * 4;
    float4 a = *(const float4*)(x1 + base);
    float4 b = *(const float4*)(x2 + base);
    float x[4] = {a.x + b.x, a.y + b.y, a.z + b.z, a.w + b.w};
    float s = x[0] + x[1] + x[2] + x[3];
    float s2 = x[0] * x[0] + x[1] * x[1] + x[2] * x[2] + x[3] * x[3];
#pragma unroll
    for (int off = 32; off; off >>= 1) { s += __shfl_xor(s, off, 64); s2 += __shfl_xor(s2, off, 64); }
    __shared__ float ps[4], ps2[4];
    int wave = tid >> 6, lane = tid & 63;
    if (lane == 0) { ps[wave] = s; ps2[wave] = s2; }
    __syncthreads();
    s  = ps[0] + ps[1] + ps[2] + ps[3];
    s2 = ps2[0] + ps2[1] + ps2[2] + ps2[3];
    float mean = s * (1.f / D_);
    float var  = s2 * (1.f / D_) - mean * mean;
    float rstd = rsqrtf(var + 1e-5f);
    float4 gg = *(const float4*)(g + tid * 4);
    float4 bb = *(const float4*)(be + tid * 4);
    float y0 = (x[0] - mean) * rstd * gg.x + bb.x;
    float y1 = (x[1] - mean) * rstd * gg.y + bb.y;
    float y2 = (x[2] - mean) * rstd * gg.z + bb.z;
    float y3 = (x[3] - mean) * rstd * gg.w + bb.w;
    float4 yo = {y0, y1, y2, y3};
    *(float4*)(outf + base) = yo;
    bf16x4 ob = {(bf16)y0, (bf16)y1, (bf16)y2, (bf16)y3};
    *(bf16x4*)(outb + base) = ob;
}

// ---------------- LN2: layernorm(sum_z parts[z] + b2 + h1) * g + be -> fp32 ----------
template<int SK>
__global__ void layernorm_res2(const float* __restrict__ parts, const float* __restrict__ b2,
                               const float* __restrict__ x2, const float* __restrict__ g,
                               const float* __restrict__ be, float* __restrict__ outf) {
    const int row = blockIdx.x, tid = threadIdx.x;
    const long base = (long)row * D_ + tid * 4;
    float4 a = *(const float4*)(parts + base);
#pragma unroll
    for (int z = 1; z < SK; z++) {
        float4 p = *(const float4*)(parts + (long)z * ROWS_ * D_ + base);
        a.x += p.x; a.y += p.y; a.z += p.z; a.w += p.w;
    }
    float4 bb2 = *(const float4*)(b2 + tid * 4);
    float4 b = *(const float4*)(x2 + base);
    float x[4] = {a.x + bb2.x + b.x, a.y + bb2.y + b.y, a.z + bb2.z + b.z, a.w + bb2.w + b.w};
    float s = x[0] + x[1] + x[2] + x[3];
    float s2 = x[0] * x[0] + x[1] * x[1] + x[2] * x[2] + x[3] * x[3];
#pragma unroll
    for (int off = 32; off; off >>= 1) { s += __shfl_xor(s, off, 64); s2 += __shfl_xor(s2, off, 64); }
    __shared__ float ps[4], ps2[4];
    int wave = tid >> 6, lane = tid & 63;
    if (lane == 0) { ps[wave] = s; ps2[wave] = s2; }
    __syncthreads();
    s  = ps[0] + ps[1] + ps[2] + ps[3];
    s2 = ps2[0] + ps2[1] + ps2[2] + ps2[3];
    float mean = s * (1.f / D_);
    float var  = s2 * (1.f / D_) - mean * mean;
    float rstd = rsqrtf(var + 1e-5f);
    float4 gg = *(const float4*)(g + tid * 4);
    float4 bb = *(const float4*)(be + tid * 4);
    float4 yo = {(x[0] - mean) * rstd * gg.x + bb.x, (x[1] - mean) * rstd * gg.y + bb.y,
                 (x[2] - mean) * rstd * gg.z + bb.z, (x[3] - mean) * rstd * gg.w + bb.w};
    *(float4*)(outf + base) = yo;
}

// ---------------- launch ----------------
extern "C" void kernel_launch(void* const* d_in, const int* in_sizes, int n_in,
                              void* d_out, int out_size, void* d_ws, size_t ws_size,
                              hipStream_t stream) {
    (void)in_sizes; (void)n_in; (void)out_size;
    const float* h   = (const float*)d_in[0];
    const float* rh  = (const float*)d_in[1];
    const float* Wq  = (const float*)d_in[2];
    const float* Wk  = (const float*)d_in[3];
    const float* Wv  = (const float*)d_in[4];
    const float* Wo  = (const float*)d_in[5];
    const float* Wrk = (const float*)d_in[6];
    const float* Wrq = (const float*)d_in[7];
    const float* W1  = (const float*)d_in[8];
    const float* b1  = (const float*)d_in[9];
    const float* W2  = (const float*)d_in[10];
    const float* b2  = (const float*)d_in[11];
    const float* g1  = (const float*)d_in[12];
    const float* be1 = (const float*)d_in[13];
    const float* g2  = (const float*)d_in[14];
    const float* be2 = (const float*)d_in[15];

    char* w = (char*)d_ws;
    size_t used = 0;
    auto alloc = [&](size_t bytes) { char* p = w + used; used += (bytes + 255) & ~(size_t)255; return p; };
    bf16*  hb   = (bf16*)alloc((size_t)ROWS_ * D_ * 2);       // 8 MB; later ctx, then h1b
    bf16*  Wqt  = (bf16*)alloc((size_t)D_ * D_ * 2);          // Wqt/Wkt/Wvt contiguous (z-batch)
    bf16*  Wkt  = (bf16*)alloc((size_t)D_ * D_ * 2);
    bf16*  Wvt  = (bf16*)alloc((size_t)D_ * D_ * 2);
    bf16*  Wot  = (bf16*)alloc((size_t)D_ * D_ * 2);
    bf16*  W1t  = (bf16*)alloc((size_t)D_ * FFN_ * 2);
    bf16*  W2t  = (bf16*)alloc((size_t)FFN_ * D_ * 2);
    bf16*  qb   = (bf16*)alloc((size_t)ROWS_ * D_ * 2);       // qb/kb/vb contiguous (z-batch out)
    bf16*  kb   = (bf16*)alloc((size_t)ROWS_ * D_ * 2);
    bf16*  vb   = (bf16*)alloc((size_t)ROWS_ * D_ * 2);
    bf16*  kT   = (bf16*)alloc((size_t)ROWS_ * D_ * 2);       // kT[m][d] = chunk[d*L+m]
    bf16*  vT   = (bf16*)alloc((size_t)ROWS_ * D_ * 2);       // vT[d][key]
    float* rq   = (float*)alloc((size_t)ROWS_ * 4 * 4);
    float* rk   = (float*)alloc((size_t)ROWS_ * 4 * 4);
    float* h1   = (float*)alloc((size_t)ROWS_ * D_ * 4);      // 16 MB, live to the end

    // ---- shared scratch region: flash K-split partials, then hsa, then FFN2 partials
    const size_t psz    = (size_t)ROWS_ * D_ * 4;             // 16 MB
    const size_t PLHD   = (size_t)PAIRS_ * L_ * HD_;          // elements
    const size_t needKS = 2 * PLHD * 4 + 2 * (size_t)PAIRS_ * L_ * 4;  // ~32.25 MB
    const size_t avail  = (ws_size > used) ? ws_size - used : 0;
    const int SK = (avail >= 4 * psz) ? 4 : (avail >= 2 * psz) ? 2 : 1;
    size_t region = (size_t)SK * psz;
    const int KS = (avail >= (needKS > region ? needKS : region)) ? 2 : 1;
    if (KS == 2 && needKS > region) region = needKS;
    float* P = (float*)alloc(region);
    float* hsa   = P;
    float* Opart = P;
    float* Osum  = P + 2 * PLHD;
    bf16* ctx = hb;
    bf16* mid = qb;    // 32 MB over qb..kT, live after flash
    bf16* h1b = hb;    // over hb, live after Wo

    const dim3 blk(256);
    const long BH = (long)L_ * HD_;

    // 1. h -> bf16
    cvt_bf16_kernel<<<ROWS_ * D_ / 1024, blk, 0, stream>>>(h, hb);
    // 2. weight transposes
    transpose_to_bf16<float><<<dim3(32, 32, 1), blk, 0, stream>>>(Wq, Wqt, D_, D_, 0, 0);
    transpose_to_bf16<float><<<dim3(32, 32, 1), blk, 0, stream>>>(Wk, Wkt, D_, D_, 0, 0);
    transpose_to_bf16<float><<<dim3(32, 32, 1), blk, 0, stream>>>(Wv, Wvt, D_, D_, 0, 0);
    transpose_to_bf16<float><<<dim3(32, 32, 1), blk, 0, stream>>>(Wo, Wot, D_, D_, 0, 0);
    transpose_to_bf16<float><<<dim3(128, 32, 1), blk, 0, stream>>>(W1, W1t, D_, FFN_, 0, 0);
    transpose_to_bf16<float><<<dim3(32, 128, 1), blk, 0, stream>>>(W2, W2t, FFN_, D_, 0, 0);
    // 3. relevance projections
    rqk_kernel<<<ROWS_ / 256, blk, 0, stream>>>(rh, Wrq, Wrk, rq, rk);
    // 4. QKV projections, z=3 batched (384 blocks, 128x256 ring-2)
    gemmA<4><<<dim3(32, 4, 3), blk, 0, stream>>>(hb, Wqt, qb, nullptr,
        ROWS_, D_, D_, D_, D_, 0, (long)D_ * D_, (long)ROWS_ * D_, 1.f);
    // 5. per-(b,n) transposes: kT[m][d] = kblk([HD][L] flat view)[d][m]; vT[d][key]
    transpose_to_bf16<bf16><<<dim3(64, 4, PAIRS_), blk, 0, stream>>>(kb, kT, HD_, L_, BH, BH);
    transpose_to_bf16<bf16><<<dim3(4, 64, PAIRS_), blk, 0, stream>>>(vb, vT, L_, HD_, BH, BH);
    // 6. fused flash attention -> ctx (K-split 2 when workspace allows)
    if (KS == 2) {
        flash_attn<2><<<dim3(16, 16, 2), blk, 0, stream>>>(qb, kT, vT, rq, rk, ctx, Opart, Osum);
        flash_reduce<2><<<PAIRS_ * L_ * HD_ / 1024, blk, 0, stream>>>(Opart, Osum, ctx);
    } else {
        flash_attn<1><<<dim3(16, 16, 1), blk, 0, stream>>>(qb, kT, vT, rq, rk, ctx, Opart, Osum);
    }
    // 7. h_sa = ctx @ Wo (fp32) — BM=128 m97-path, grid 32x8 = 256 blocks
    gemm128<128, 0><<<dim3(32, 8, 1), blk, 0, stream>>>(ctx, Wot, hsa, nullptr,
        ROWS_, D_, D_, D_, D_, 0, 0, 0, 1.f);
    // 8. h1 = LN(h_sa + h)
    layernorm_res<<<ROWS_, blk, 0, stream>>>(hsa, h, g1, be1, h1, h1b);
    // 9. mid = relu(h1 @ W1 + b1)  (512 blocks, 128x256 ring-2)
    gemmA<7><<<dim3(32, 16, 1), blk, 0, stream>>>(h1b, W1t, mid, b1,
        ROWS_, FFN_, D_, D_, D_, 0, 0, 0, 1.f);
    // 10-11. hf partials ; out = LN(h1 + sum + b2)
    {
        const int KC = FFN_ / SK;
        if (SK == 4) {
            gemmA<0><<<dim3(32, 4, 4), blk, 0, stream>>>(mid, W2t, P, nullptr,
                ROWS_, D_, KC, FFN_, FFN_, KC, KC, (long)ROWS_ * D_, 1.f);
            layernorm_res2<4><<<ROWS_, blk, 0, stream>>>(P, b2, h1, g2, be2, (float*)d_out);
        } else if (SK == 2) {
            gemmA<0><<<dim3(32, 4, 2), blk, 0, stream>>>(mid, W2t, P, nullptr,
                ROWS_, D_, KC, FFN_, FFN_, KC, KC, (long)ROWS_ * D_, 1.f);
            layernorm_res2<2><<<ROWS_, blk, 0, stream>>>(P, b2, h1, g2, be2, (float*)d_out);
        } else {
            gemm128<128, 0><<<dim3(32, 8, 1), blk, 0, stream>>>(mid, W2t, P, nullptr,
                ROWS_, D_, FFN_, FFN_, FFN_, 0, 0, 0, 1.f);
            layernorm_res2<1><<<ROWS_, blk, 0, stream>>>(P, b2, h1, g2, be2, (float*)d_out);
        }
    }
}

// Round 8
// 378.132 us; speedup vs baseline: 1.2600x; 1.2600x over previous
//
#include <hip/hip_runtime.h>

typedef __bf16 bf16;
typedef __bf16 bf16x8 __attribute__((ext_vector_type(8)));
typedef __bf16 bf16x4 __attribute__((ext_vector_type(4)));
typedef float  f32x4  __attribute__((ext_vector_type(4)));

#define D_     1024
#define FFN_   4096
#define NH_    8
#define HD_    128
#define L_     2048
#define B_     2
#define ROWS_  4096           // B_*L_
#define PAIRS_ 16             // B_*NH_
#define KT_    64             // flash K-tile (keys)
#define PSTR   72             // Ps row stride (bf16): 144 B = 16B-aligned rows
#define ALPHA_  0.08838834764831845f   // 1/sqrt(128)
#define RSCALE_ 5.656854249492381f     // 0.5/ALPHA_

// async 16B global -> LDS (wave-uniform LDS base + lane*16 implicit)
__device__ __forceinline__ void async16(const bf16* g, bf16* l) {
    __builtin_amdgcn_global_load_lds(
        (const __attribute__((address_space(1))) unsigned int*)g,
        (__attribute__((address_space(3))) unsigned int*)l, 16, 0, 0);
}
__device__ __forceinline__ f32x4 MFMA(bf16x8 a, bf16x8 b, f32x4 c) {
    return __builtin_amdgcn_mfma_f32_16x16x32_bf16(a, b, c, 0, 0, 0);
}

// ---------------- elementwise fp32 -> bf16 ----------------
__global__ void cvt_bf16_kernel(const float* __restrict__ in, bf16* __restrict__ out) {
    long i = ((long)blockIdx.x * 256 + threadIdx.x) * 4;
    float4 v = *(const float4*)(in + i);
    bf16x4 o = {(bf16)v.x, (bf16)v.y, (bf16)v.z, (bf16)v.w};
    *(bf16x4*)(out + i) = o;
}

// ---------------- tiled transpose (TI -> bf16), batched over z ----------------
template<typename TI>
__global__ void transpose_to_bf16(const TI* __restrict__ in, bf16* __restrict__ out,
                                  int r, int c, long sIn, long sOut) {
    __shared__ bf16 t[32][33];
    long zi = (long)blockIdx.z * sIn;
    long zo = (long)blockIdx.z * sOut;
    int x0 = blockIdx.x * 32, y0 = blockIdx.y * 32;
    int tx = threadIdx.x & 31, ty = threadIdx.x >> 5;  // 32 x 8
#pragma unroll
    for (int i = 0; i < 4; i++)
        t[ty + i * 8][tx] = (bf16)in[zi + (long)(y0 + ty + i * 8) * c + x0 + tx];
    __syncthreads();
#pragma unroll
    for (int i = 0; i < 4; i++)
        out[zo + (long)(x0 + ty + i * 8) * r + y0 + tx] = t[tx][ty + i * 8];
}

// ---- fused 4x DxD fp32->bf16 transpose (Wq/Wk/Wv/Wo in one dispatch) ----
__global__ void transpose4_to_bf16(const float* __restrict__ p0, const float* __restrict__ p1,
                                   const float* __restrict__ p2, const float* __restrict__ p3,
                                   bf16* __restrict__ o0, bf16* __restrict__ o1,
                                   bf16* __restrict__ o2, bf16* __restrict__ o3) {
    const float* in; bf16* out;
    switch (blockIdx.z) {
        case 0:  in = p0; out = o0; break;
        case 1:  in = p1; out = o1; break;
        case 2:  in = p2; out = o2; break;
        default: in = p3; out = o3; break;
    }
    __shared__ bf16 t[32][33];
    int x0 = blockIdx.x * 32, y0 = blockIdx.y * 32;
    int tx = threadIdx.x & 31, ty = threadIdx.x >> 5;  // 32 x 8
#pragma unroll
    for (int i = 0; i < 4; i++)
        t[ty + i * 8][tx] = (bf16)in[(long)(y0 + ty + i * 8) * D_ + x0 + tx];
    __syncthreads();
#pragma unroll
    for (int i = 0; i < 4; i++)
        out[(long)(x0 + ty + i * 8) * D_ + y0 + tx] = t[tx][ty + i * 8];
}

// ---------------- tiny relevance projections ----------------
__global__ void rqk_kernel(const float* __restrict__ rh, const float* __restrict__ Wrq,
                           const float* __restrict__ Wrk, float* __restrict__ rq,
                           float* __restrict__ rk) {
    int t = blockIdx.x * 256 + threadIdx.x;
    float4 r = *(const float4*)(rh + (long)t * 4);
    float q[4], k[4];
#pragma unroll
    for (int c = 0; c < 4; c++) {
        q[c] = r.x * Wrq[c] + r.y * Wrq[4 + c] + r.z * Wrq[8 + c] + r.w * Wrq[12 + c];
        k[c] = r.x * Wrk[c] + r.y * Wrk[4 + c] + r.z * Wrk[8 + c] + r.w * Wrk[12 + c];
    }
    float4 qo = {q[0], q[1], q[2], q[3]};
    float4 ko = {k[0], k[1], k[2], k[3]};
    *(float4*)(rq + (long)t * 4) = qo;
    *(float4*)(rk + (long)t * 4) = ko;
}

// ---------------- m97-style MFMA GEMM (Wo + fallback) ----------------
template<int BM, int EPI>
__launch_bounds__(256)
__global__ void gemm128(const bf16* __restrict__ A, const bf16* __restrict__ Bt,
                        void* __restrict__ Cv, const float* __restrict__ bias,
                        int M, int N, int K, int lda, int ldb,
                        long sA, long sB, long sC, float alpha) {
    constexpr int RF = (BM == 128) ? 4 : 2;
    __shared__ __align__(16) bf16 As[BM * 32];
    __shared__ __align__(16) bf16 Bs[128 * 32];
    const int tid  = threadIdx.x;
    const int wave = tid >> 6, lane = tid & 63;
    const int quad = lane >> 4, mr = lane & 15;
    const int bM = blockIdx.x * BM, bN = blockIdx.y * 128;
    A  += (long)blockIdx.z * sA;
    Bt += (long)blockIdx.z * sB;
    const int wr = (wave >> 1) * (BM / 2), wc = (wave & 1) * 64;

    f32x4 acc[RF][4];
#pragma unroll
    for (int r = 0; r < RF; r++)
#pragma unroll
        for (int c = 0; c < 4; c++) { f32x4 z = {0.f, 0.f, 0.f, 0.f}; acc[r][c] = z; }

    const int scol = (lane & 3) * 8;
    const bf16* Ag0; const bf16* Ag1 = nullptr;
    if (BM == 128) {
        const int srow = wave * 32 + (lane >> 2);
        Ag0 = A + (long)(bM + srow) * lda + scol;
        Ag1 = Ag0 + (long)16 * lda;
    } else {
        const int srow = wave * 16 + (lane >> 2);
        Ag0 = A + (long)(bM + srow) * lda + scol;
    }
    const int srowB = wave * 32 + (lane >> 2);
    const bf16* Bg0 = Bt + (long)(bN + srowB) * ldb + scol;
    const bf16* Bg1 = Bg0 + (long)16 * ldb;
    bf16* AsW = As + wave * (BM == 128 ? 1024 : 512);
    bf16* BsW = Bs + wave * 1024;

    for (int k0 = 0; k0 < K; k0 += 32) {
        if (BM == 128) { async16(Ag0, AsW); async16(Ag1, AsW + 512); Ag0 += 32; Ag1 += 32; }
        else           { async16(Ag0, AsW); Ag0 += 32; }
        async16(Bg0, BsW); async16(Bg1, BsW + 512);
        Bg0 += 32; Bg1 += 32;
        __syncthreads();
        bf16x8 af[RF], bfv[4];
#pragma unroll
        for (int r = 0; r < RF; r++)
            af[r] = *(const bf16x8*)(&As[(wr + r * 16 + mr) * 32 + quad * 8]);
#pragma unroll
        for (int c = 0; c < 4; c++)
            bfv[c] = *(const bf16x8*)(&Bs[(wc + c * 16 + mr) * 32 + quad * 8]);
#pragma unroll
        for (int r = 0; r < RF; r++)
#pragma unroll
            for (int c = 0; c < 4; c++)
                acc[r][c] = MFMA(af[r], bfv[c], acc[r][c]);
        __syncthreads();
    }

    const long zC = (long)blockIdx.z * sC;
    float bias_c[4];
    if (EPI & 1) {
#pragma unroll
        for (int c = 0; c < 4; c++) bias_c[c] = bias[bN + wc + c * 16 + mr];
    }
#pragma unroll
    for (int r = 0; r < RF; r++) {
#pragma unroll
        for (int c = 0; c < 4; c++) {
            const long col = bN + wc + c * 16 + mr;
#pragma unroll
            for (int i = 0; i < 4; i++) {
                const long row = bM + wr + r * 16 + quad * 4 + i;
                float v = acc[r][c][i] * alpha;
                if (EPI & 1) v += bias_c[c];
                if (EPI & 2) v = fmaxf(v, 0.f);
                if (EPI & 4) ((bf16*)Cv)[zC + row * (long)N + col] = (bf16)v;
                else         ((float*)Cv)[zC + row * (long)N + col] = v;
            }
        }
    }
}

// ---------------- 256x256 8-phase pipelined MFMA GEMM (T2+T3+T4+T5) ----------------
// Ring-4 LDS with counted vmcnt(8): ~3 K-tiles of prefetch cover. Measured ~52 us
// per FFN-sized dispatch (vs 66 gemm128, 78 depth-1 gemmA) — the prefetch DEPTH is
// the lever, not residency (VGPR caps waves at 2/SIMD regardless).
template<int EPI>
__launch_bounds__(512, 2)
__global__ void gemm256(const bf16* __restrict__ A, const bf16* __restrict__ Bt,
                        void* __restrict__ Cv, const float* __restrict__ bias,
                        int M, int N, int K, int lda, int ldb,
                        long sA, long sB, long sC, float alpha) {
    __shared__ __align__(16) bf16 LA[4][256 * 32];   // 4 x 16 KB
    __shared__ __align__(16) bf16 LB[4][256 * 32];   // 4 x 16 KB
    const int tid = threadIdx.x, wave = tid >> 6, lane = tid & 63;
    const int quad = lane >> 4, mr = lane & 15;
    const int wr = wave >> 2, wc = wave & 3;
    const int bM = blockIdx.x * 256, bN = blockIdx.y * 256;
    (void)M;
    A  += (long)blockIdx.z * sA;
    Bt += (long)blockIdx.z * sB;

    const int srow = tid >> 2;
    const int sg   = (((tid & 3) ^ ((tid >> 3) & 3))) * 8;
    const bf16* Ag = A  + (long)(bM + srow) * lda + sg;
    const bf16* Bg = Bt + (long)(bN + srow) * ldb + sg;

    auto stageA = [&](int slot, int kt) {
        const bf16* s = Ag + kt * 32;
        async16(s,                   &LA[slot][wave * 512]);
        async16(s + (long)128 * lda, &LA[slot][4096 + wave * 512]);
    };
    auto stageB = [&](int slot, int kt) {
        const bf16* s = Bg + kt * 32;
        async16(s,                   &LB[slot][wave * 512]);
        async16(s + (long)128 * ldb, &LB[slot][4096 + wave * 512]);
    };

    f32x4 acc[8][4];
#pragma unroll
    for (int f = 0; f < 8; f++)
#pragma unroll
        for (int n = 0; n < 4; n++) { f32x4 z = {0.f, 0.f, 0.f, 0.f}; acc[f][n] = z; }

    const int gsw = (quad ^ ((mr >> 1) & 3)) * 8;

    stageA(0, 0); stageB(0, 0);
    stageA(1, 1); stageB(1, 1);
    stageA(2, 2); stageB(2, 2);
    asm volatile("s_waitcnt vmcnt(8)" ::: "memory");
    __builtin_amdgcn_s_barrier();

    const int NT = K >> 5;
    for (int t = 0; t < NT; ++t) {
        const int slot = t & 3;
        const bf16* As = &LA[slot][0];
        const bf16* Bs = &LB[slot][0];

        bf16x8 a0[4], bb[4];
#pragma unroll
        for (int f = 0; f < 4; f++)
            a0[f] = *(const bf16x8*)(As + (wr * 128 + f * 16 + mr) * 32 + gsw);
#pragma unroll
        for (int n = 0; n < 4; n++)
            bb[n] = *(const bf16x8*)(Bs + (wc * 64 + n * 16 + mr) * 32 + gsw);
        if (t + 3 < NT) stageA((t + 3) & 3, t + 3);
        __builtin_amdgcn_s_barrier();
        asm volatile("s_waitcnt lgkmcnt(0)" ::: "memory");
        __builtin_amdgcn_sched_barrier(0);
        __builtin_amdgcn_s_setprio(1);
#pragma unroll
        for (int f = 0; f < 4; f++)
#pragma unroll
            for (int n = 0; n < 4; n++)
                acc[f][n] = MFMA(a0[f], bb[n], acc[f][n]);
        __builtin_amdgcn_s_setprio(0);
        __builtin_amdgcn_s_barrier();

        bf16x8 a1[4];
#pragma unroll
        for (int f = 0; f < 4; f++)
            a1[f] = *(const bf16x8*)(As + (wr * 128 + 64 + f * 16 + mr) * 32 + gsw);
        if (t + 3 < NT) stageB((t + 3) & 3, t + 3);
        __builtin_amdgcn_s_barrier();
        asm volatile("s_waitcnt lgkmcnt(0)" ::: "memory");
        __builtin_amdgcn_sched_barrier(0);
        __builtin_amdgcn_s_setprio(1);
#pragma unroll
        for (int f = 0; f < 4; f++)
#pragma unroll
            for (int n = 0; n < 4; n++)
                acc[4 + f][n] = MFMA(a1[f], bb[n], acc[4 + f][n]);
        __builtin_amdgcn_s_setprio(0);
        if (t < NT - 3)       asm volatile("s_waitcnt vmcnt(8)" ::: "memory");
        else if (t == NT - 3) asm volatile("s_waitcnt vmcnt(4)" ::: "memory");
        else if (t == NT - 2) asm volatile("s_waitcnt vmcnt(0)" ::: "memory");
        __builtin_amdgcn_s_barrier();
    }

    const long zC = (long)blockIdx.z * sC;
    float bias_c[4];
    if (EPI & 1) {
#pragma unroll
        for (int n = 0; n < 4; n++) bias_c[n] = bias[bN + wc * 64 + n * 16 + mr];
    }
#pragma unroll
    for (int f = 0; f < 8; f++) {
#pragma unroll
        for (int n = 0; n < 4; n++) {
            const long col = bN + wc * 64 + n * 16 + mr;
#pragma unroll
            for (int i = 0; i < 4; i++) {
                const long row = bM + wr * 128 + f * 16 + quad * 4 + i;
                float v = acc[f][n][i] * alpha;
                if (EPI & 1) v += bias_c[n];
                if (EPI & 2) v = fmaxf(v, 0.f);
                if (EPI & 4) ((bf16*)Cv)[zC + row * (long)N + col] = (bf16)v;
                else         ((float*)Cv)[zC + row * (long)N + col] = v;
            }
        }
    }
}

// ---------------- fused flash attention with relevance bias, K-split ----------------
// Round-3/4 proven body (4 waves, 128-row Q-tile, single-buffered 2-barrier loop,
// 51 KB LDS) + T1 bijective XCD chunking (FETCH 74->17 MB verified) + T5 setprio.
template<int SPLIT>
__launch_bounds__(256, 1)
__global__ void flash_attn(const bf16* __restrict__ qb, const bf16* __restrict__ kT,
                           const bf16* __restrict__ vT, const float* __restrict__ rq,
                           const float* __restrict__ rk, bf16* __restrict__ ctx,
                           float* __restrict__ opart, float* __restrict__ osum) {
    __shared__ __align__(16) bf16  Ksh[KT_ * HD_];   // [key][d], granule-swizzled
    __shared__ __align__(16) bf16  Vsh[HD_ * KT_];   // [d][key], granule-swizzled
    __shared__ __align__(16) float rks[4 * KT_];     // [r][key] fp32
    __shared__ __align__(16) bf16  Ps[4][32 * PSTR]; // per-wave P, 16B-aligned rows

    const int tid = threadIdx.x, wave = tid >> 6, lane = tid & 63;
    const int quad = lane >> 4, mr = lane & 15;
    // T1: bijective XCD chunking. grid (16,16,SPLIT) -> nwg = 256*SPLIT (div by 8).
    const int nwg = 256 * SPLIT;
    const int lid = blockIdx.x + (blockIdx.y << 4) + (blockIdx.z << 8);
    const int wid = (lid & 7) * (nwg >> 3) + (lid >> 3);
    const int ksp = wid >> 8;
    const int pair = (wid >> 4) & 15, b = pair >> 3;
    const int bQ = (wid & 15) * 128;
    const long PB = (long)pair * L_ * HD_;
    const bf16* Qg = qb + PB;
    const bf16* Kg = kT + PB;
    const bf16* Vg = vT + PB;
    const float* rkb = rk + (long)b * L_ * 4;

    // Q fragments in registers (A-layout): rows bQ + wave*32 + f*16 + mr
    bf16x8 Qf[2][4], Qe[2];
#pragma unroll
    for (int f = 0; f < 2; f++) {
#pragma unroll
        for (int t = 0; t < 4; t++)
            Qf[f][t] = *(const bf16x8*)(Qg + (long)(bQ + wave * 32 + f * 16 + mr) * HD_ + t * 32 + quad * 8);
        bf16x8 z = {};
        if (quad == 0) {
            float4 v = *(const float4*)(rq + ((long)b * L_ + bQ + wave * 32 + f * 16 + mr) * 4);
            z[0] = (bf16)(v.x * RSCALE_); z[1] = (bf16)(v.y * RSCALE_);
            z[2] = (bf16)(v.z * RSCALE_); z[3] = (bf16)(v.w * RSCALE_);
        }
        Qe[f] = z;
    }

    bf16x8 ones;
#pragma unroll
    for (int j = 0; j < 8; j++) ones[j] = (bf16)1.0f;

    f32x4 O[2][8], Os[2];
#pragma unroll
    for (int f = 0; f < 2; f++) {
#pragma unroll
        for (int c = 0; c < 8; c++) { f32x4 z = {0.f, 0.f, 0.f, 0.f}; O[f][c] = z; }
        f32x4 z = {0.f, 0.f, 0.f, 0.f}; Os[f] = z;
    }

    const int tile0 = ksp * ((L_ / KT_) / SPLIT);
    const int tile1 = tile0 + (L_ / KT_) / SPLIT;
    for (int kt = tile0; kt < tile1; kt++) {
        const int kt0 = kt * KT_;
        // ---- stage K/V/rk (single buffer) ----
#pragma unroll
        for (int it = 0; it < 4; it++) {
            int G = it * 256 + tid;
            int r1 = G >> 4, g1 = (G & 15) ^ (r1 & 15);
            async16(Kg + (long)(kt0 + r1) * HD_ + g1 * 8, &Ksh[(it * 256 + wave * 64) * 8]);
            int r2 = G >> 3, g2 = (G & 7) ^ (r2 & 7);
            async16(Vg + (long)r2 * L_ + kt0 + g2 * 8, &Vsh[(it * 256 + wave * 64) * 8]);
        }
        if (tid < 64) {
            int r3 = tid >> 4, g3 = tid & 15;
            async16((const bf16*)(rkb + (long)r3 * L_ + kt0 + g3 * 4), (bf16*)&rks[0]);
        }
        __syncthreads();   // drains vmcnt -> LDS valid for all waves

        bf16* PsW = Ps[wave];

        // ---- S = Q K^T (+ ext bias chunk), 4 col-blocks of 16 keys ----
        f32x4 sc[4][2];
        __builtin_amdgcn_s_setprio(1);
#pragma unroll
        for (int c = 0; c < 4; c++) {
            f32x4 s0 = {0.f, 0.f, 0.f, 0.f}, s1 = s0;
#pragma unroll
            for (int t = 0; t < 4; t++) {
                bf16x8 kf = *(const bf16x8*)(Ksh + (c * 16 + mr) * HD_ + (((t * 4 + quad) ^ mr) * 8));
                s0 = MFMA(Qf[0][t], kf, s0);
                s1 = MFMA(Qf[1][t], kf, s1);
            }
            bf16x8 ke = {};
            if (quad == 0) {
                ke[0] = (bf16)rks[0 * KT_ + c * 16 + mr];
                ke[1] = (bf16)rks[1 * KT_ + c * 16 + mr];
                ke[2] = (bf16)rks[2 * KT_ + c * 16 + mr];
                ke[3] = (bf16)rks[3 * KT_ + c * 16 + mr];
            }
            s0 = MFMA(Qe[0], ke, s0);
            s1 = MFMA(Qe[1], ke, s1);
            sc[c][0] = s0; sc[c][1] = s1;
        }
        __builtin_amdgcn_s_setprio(0);

        // ---- P = exp(ALPHA*S) straight to LDS (no max, no shuffles) ----
#pragma unroll
        for (int f = 0; f < 2; f++) {
#pragma unroll
            for (int i = 0; i < 4; i++) {
                const int prow = (f * 16 + quad * 4 + i) * PSTR;
                PsW[prow + 0 * 16 + mr] = (bf16)__expf(sc[0][f][i] * ALPHA_);
                PsW[prow + 1 * 16 + mr] = (bf16)__expf(sc[1][f][i] * ALPHA_);
                PsW[prow + 2 * 16 + mr] = (bf16)__expf(sc[2][f][i] * ALPHA_);
                PsW[prow + 3 * 16 + mr] = (bf16)__expf(sc[3][f][i] * ALPHA_);
            }
        }

        // ---- O += P @ V ; Os += P @ ones (row sums) ----
        __builtin_amdgcn_s_setprio(1);
#pragma unroll
        for (int t = 0; t < 2; t++) {
            bf16x8 pf0 = *(const bf16x8*)(PsW + (0 * 16 + mr) * PSTR + t * 32 + quad * 8);
            bf16x8 pf1 = *(const bf16x8*)(PsW + (1 * 16 + mr) * PSTR + t * 32 + quad * 8);
            Os[0] = MFMA(pf0, ones, Os[0]);
            Os[1] = MFMA(pf1, ones, Os[1]);
#pragma unroll
            for (int c2 = 0; c2 < 8; c2++) {
                bf16x8 vf = *(const bf16x8*)(Vsh + (c2 * 16 + mr) * KT_ + (((t * 4 + quad) ^ (mr & 7)) * 8));
                O[0][c2] = MFMA(pf0, vf, O[0][c2]);
                O[1][c2] = MFMA(pf1, vf, O[1][c2]);
            }
        }
        __builtin_amdgcn_s_setprio(0);
        __syncthreads();   // all waves done reading K/V before restage
    }

    // ---- epilogue ----
    if (SPLIT == 1) {
        bf16* Cg = ctx + PB;
#pragma unroll
        for (int f = 0; f < 2; f++)
#pragma unroll
            for (int i = 0; i < 4; i++) {
                const float inv = 1.f / Os[f][i];
                const long row = bQ + wave * 32 + f * 16 + quad * 4 + i;
#pragma unroll
                for (int c2 = 0; c2 < 8; c2++)
                    Cg[row * HD_ + c2 * 16 + mr] = (bf16)(O[f][c2][i] * inv);
            }
    } else {
        float* Og = opart + (long)ksp * ((long)PAIRS_ * L_ * HD_) + PB;
        float* Sg = osum + (long)ksp * (PAIRS_ * L_) + pair * L_;
#pragma unroll
        for (int f = 0; f < 2; f++)
#pragma unroll
            for (int i = 0; i < 4; i++) {
                const long row = bQ + wave * 32 + f * 16 + quad * 4 + i;
#pragma unroll
                for (int c2 = 0; c2 < 8; c2++)
                    Og[row * HD_ + c2 * 16 + mr] = O[f][c2][i];
                if (mr == 0) Sg[row] = Os[f][i];
            }
    }
}

// --------- combine KS flash partials: ctx = (sum O_z) / (sum s_z) ----------
template<int KS>
__global__ void flash_reduce(const float* __restrict__ op, const float* __restrict__ os,
                             bf16* __restrict__ ctx) {
    const long PLHD = (long)PAIRS_ * L_ * HD_;
    long e = ((long)blockIdx.x * 256 + threadIdx.x) * 4;
    long row = e >> 7;                       // / HD_
    float4 a = *(const float4*)(op + e);
    float s = os[row];
#pragma unroll
    for (int z = 1; z < KS; z++) {
        float4 p = *(const float4*)(op + (long)z * PLHD + e);
        a.x += p.x; a.y += p.y; a.z += p.z; a.w += p.w;
        s += os[(long)z * PAIRS_ * L_ + row];
    }
    float inv = 1.f / s;
    bf16x4 o = {(bf16)(a.x * inv), (bf16)(a.y * inv),
                (bf16)(a.z * inv), (bf16)(a.w * inv)};
    *(bf16x4*)(ctx + e) = o;
}

// ---------------- LN1: layernorm(x1 + x2) * g + be ; fp32 + bf16 out ----------------
__global__ void layernorm_res(const float* __restrict__ x1, const float* __restrict__ x2,
                              const float* __restrict__ g, const float* __restrict__ be,
                              float* __restrict__ outf, bf16* __restrict__ outb) {
    const int row = blockIdx.x, tid = threadIdx.x;
    const long base = (long)row * D_ + tid * 4;
    float4 a = *(const float4*)(x1 + base);
    float4 b = *(const float4*)(x2 + base);
    float x[4] = {a.x + b.x, a.y + b.y, a.z + b.z, a.w + b.w};
    float s = x[0] + x[1] + x[2] + x[3];
    float s2 = x[0] * x[0] + x[1] * x[1] + x[2] * x[2] + x[3] * x[3];
#pragma unroll
    for (int off = 32; off; off >>= 1) { s += __shfl_xor(s, off, 64); s2 += __shfl_xor(s2, off, 64); }
    __shared__ float ps[4], ps2[4];
    int wave = tid >> 6, lane = tid & 63;
    if (lane == 0) { ps[wave] = s; ps2[wave] = s2; }
    __syncthreads();
    s  = ps[0] + ps[1] + ps[2] + ps[3];
    s2 = ps2[0] + ps2[1] + ps2[2] + ps2[3];
    float mean = s * (1.f / D_);
    float var  = s2 * (1.f / D_) - mean * mean;
    float rstd = rsqrtf(var + 1e-5f);
    float4 gg = *(const float4*)(g + tid * 4);
    float4 bb = *(const float4*)(be + tid * 4);
    float y0 = (x[0] - mean) * rstd * gg.x + bb.x;
    float y1 = (x[1] - mean) * rstd * gg.y + bb.y;
    float y2 = (x[2] - mean) * rstd * gg.z + bb.z;
    float y3 = (x[3] - mean) * rstd * gg.w + bb.w;
    float4 yo = {y0, y1, y2, y3};
    *(float4*)(outf + base) = yo;
    bf16x4 ob = {(bf16)y0, (bf16)y1, (bf16)y2, (bf16)y3};
    *(bf16x4*)(outb + base) = ob;
}

// ---------------- LN2: layernorm(sum_z parts[z] + b2 + h1) * g + be -> fp32 ----------
template<int SK>
__global__ void layernorm_res2(const float* __restrict__ parts, const float* __restrict__ b2,
                               const float* __restrict__ x2, const float* __restrict__ g,
                               const float* __restrict__ be, float* __restrict__ outf) {
    const int row = blockIdx.x, tid = threadIdx.x;
    const long base = (long)row * D_ + tid * 4;
    float4 a = *(const float4*)(parts + base);
#pragma unroll
    for (int z = 1; z < SK; z++) {
        float4 p = *(const float4*)(parts + (long)z * ROWS_ * D_ + base);
        a.x += p.x; a.y += p.y; a.z += p.z; a.w += p.w;
    }
    float4 bb2 = *(const float4*)(b2 + tid * 4);
    float4 b = *(const float4*)(x2 + base);
    float x[4] = {a.x + bb2.x + b.x, a.y + bb2.y + b.y, a.z + bb2.z + b.z, a.w + bb2.w + b.w};
    float s = x[0] + x[1] + x[2] + x[3];
    float s2 = x[0] * x[0] + x[1] * x[1] + x[2] * x[2] + x[3] * x[3];
#pragma unroll
    for (int off = 32; off; off >>= 1) { s += __shfl_xor(s, off, 64); s2 += __shfl_xor(s2, off, 64); }
    __shared__ float ps[4], ps2[4];
    int wave = tid >> 6, lane = tid & 63;
    if (lane == 0) { ps[wave] = s; ps2[wave] = s2; }
    __syncthreads();
    s  = ps[0] + ps[1] + ps[2] + ps[3];
    s2 = ps2[0] + ps2[1] + ps2[2] + ps2[3];
    float mean = s * (1.f / D_);
    float var  = s2 * (1.f / D_) - mean * mean;
    float rstd = rsqrtf(var + 1e-5f);
    float4 gg = *(const float4*)(g + tid * 4);
    float4 bb = *(const float4*)(be + tid * 4);
    float4 yo = {(x[0] - mean) * rstd * gg.x + bb.x, (x[1] - mean) * rstd * gg.y + bb.y,
                 (x[2] - mean) * rstd * gg.z + bb.z, (x[3] - mean) * rstd * gg.w + bb.w};
    *(float4*)(outf + base) = yo;
}

// ---------------- launch ----------------
extern "C" void kernel_launch(void* const* d_in, const int* in_sizes, int n_in,
                              void* d_out, int out_size, void* d_ws, size_t ws_size,
                              hipStream_t stream) {
    (void)in_sizes; (void)n_in; (void)out_size;
    const float* h   = (const float*)d_in[0];
    const float* rh  = (const float*)d_in[1];
    const float* Wq  = (const float*)d_in[2];
    const float* Wk  = (const float*)d_in[3];
    const float* Wv  = (const float*)d_in[4];
    const float* Wo  = (const float*)d_in[5];
    const float* Wrk = (const float*)d_in[6];
    const float* Wrq = (const float*)d_in[7];
    const float* W1  = (const float*)d_in[8];
    const float* b1  = (const float*)d_in[9];
    const float* W2  = (const float*)d_in[10];
    const float* b2  = (const float*)d_in[11];
    const float* g1  = (const float*)d_in[12];
    const float* be1 = (const float*)d_in[13];
    const float* g2  = (const float*)d_in[14];
    const float* be2 = (const float*)d_in[15];

    char* w = (char*)d_ws;
    size_t used = 0;
    auto alloc = [&](size_t bytes) { char* p = w + used; used += (bytes + 255) & ~(size_t)255; return p; };
    bf16*  hb   = (bf16*)alloc((size_t)ROWS_ * D_ * 2);       // 8 MB; later ctx, then h1b
    bf16*  Wqt  = (bf16*)alloc((size_t)D_ * D_ * 2);          // Wqt/Wkt/Wvt contiguous (z-batch)
    bf16*  Wkt  = (bf16*)alloc((size_t)D_ * D_ * 2);
    bf16*  Wvt  = (bf16*)alloc((size_t)D_ * D_ * 2);
    bf16*  Wot  = (bf16*)alloc((size_t)D_ * D_ * 2);
    bf16*  W1t  = (bf16*)alloc((size_t)D_ * FFN_ * 2);
    bf16*  W2t  = (bf16*)alloc((size_t)FFN_ * D_ * 2);
    bf16*  qb   = (bf16*)alloc((size_t)ROWS_ * D_ * 2);       // qb/kb/vb contiguous (z-batch out)
    bf16*  kb   = (bf16*)alloc((size_t)ROWS_ * D_ * 2);
    bf16*  vb   = (bf16*)alloc((size_t)ROWS_ * D_ * 2);
    bf16*  kT   = (bf16*)alloc((size_t)ROWS_ * D_ * 2);       // kT[m][d] = chunk[d*L+m]
    bf16*  vT   = (bf16*)alloc((size_t)ROWS_ * D_ * 2);       // vT[d][key]
    float* rq   = (float*)alloc((size_t)ROWS_ * 4 * 4);
    float* rk   = (float*)alloc((size_t)ROWS_ * 4 * 4);
    float* h1   = (float*)alloc((size_t)ROWS_ * D_ * 4);      // 16 MB, live to the end

    // ---- shared scratch region: flash K-split partials, then hsa, then FFN2 partials
    const size_t psz    = (size_t)ROWS_ * D_ * 4;             // 16 MB
    const size_t PLHD   = (size_t)PAIRS_ * L_ * HD_;          // elements
    const size_t needKS = 2 * PLHD * 4 + 2 * (size_t)PAIRS_ * L_ * 4;  // ~32.25 MB
    const size_t avail  = (ws_size > used) ? ws_size - used : 0;
    const int SK = (avail >= 4 * psz) ? 4 : (avail >= 2 * psz) ? 2 : 1;
    size_t region = (size_t)SK * psz;
    const int KS = (avail >= (needKS > region ? needKS : region)) ? 2 : 1;
    if (KS == 2 && needKS > region) region = needKS;
    float* P = (float*)alloc(region);
    float* hsa   = P;
    float* Opart = P;
    float* Osum  = P + 2 * PLHD;
    bf16* ctx = hb;
    bf16* mid = qb;    // 32 MB over qb..kT, live after flash
    bf16* h1b = hb;    // over hb, live after Wo

    const dim3 blk(256);
    const dim3 blk512(512);
    const long BH = (long)L_ * HD_;

    // 1. h -> bf16
    cvt_bf16_kernel<<<ROWS_ * D_ / 1024, blk, 0, stream>>>(h, hb);
    // 2. weight transposes: Wq/Wk/Wv/Wo fused into ONE dispatch, W1/W2 separate shapes
    transpose4_to_bf16<<<dim3(32, 32, 4), blk, 0, stream>>>(Wq, Wk, Wv, Wo, Wqt, Wkt, Wvt, Wot);
    transpose_to_bf16<float><<<dim3(128, 32, 1), blk, 0, stream>>>(W1, W1t, D_, FFN_, 0, 0);
    transpose_to_bf16<float><<<dim3(32, 128, 1), blk, 0, stream>>>(W2, W2t, FFN_, D_, 0, 0);
    // 3. relevance projections
    rqk_kernel<<<ROWS_ / 256, blk, 0, stream>>>(rh, Wrq, Wrk, rq, rk);
    // 4. QKV projections, z=3 batched (192 blocks, 256^2 ring-4)
    gemm256<4><<<dim3(16, 4, 3), blk512, 0, stream>>>(hb, Wqt, qb, nullptr,
        ROWS_, D_, D_, D_, D_, 0, (long)D_ * D_, (long)ROWS_ * D_, 1.f);
    // 5. per-(b,n) transposes: kT[m][d] = kblk([HD][L] flat view)[d][m]; vT[d][key]
    transpose_to_bf16<bf16><<<dim3(64, 4, PAIRS_), blk, 0, stream>>>(kb, kT, HD_, L_, BH, BH);
    transpose_to_bf16<bf16><<<dim3(4, 64, PAIRS_), blk, 0, stream>>>(vb, vT, L_, HD_, BH, BH);
    // 6. fused flash attention -> ctx (K-split 2 when workspace allows)
    if (KS == 2) {
        flash_attn<2><<<dim3(16, 16, 2), blk, 0, stream>>>(qb, kT, vT, rq, rk, ctx, Opart, Osum);
        flash_reduce<2><<<PAIRS_ * L_ * HD_ / 1024, blk, 0, stream>>>(Opart, Osum, ctx);
    } else {
        flash_attn<1><<<dim3(16, 16, 1), blk, 0, stream>>>(qb, kT, vT, rq, rk, ctx, Opart, Osum);
    }
    // 7. h_sa = ctx @ Wo (fp32) — BM=64 m97-path, grid 64x8 = 512 blocks
    gemm128<64, 0><<<dim3(64, 8, 1), blk, 0, stream>>>(ctx, Wot, hsa, nullptr,
        ROWS_, D_, D_, D_, D_, 0, 0, 0, 1.f);
    // 8. h1 = LN(h_sa + h)
    layernorm_res<<<ROWS_, blk, 0, stream>>>(hsa, h, g1, be1, h1, h1b);
    // 9. mid = relu(h1 @ W1 + b1)  (256 blocks, 256^2 ring-4)
    gemm256<7><<<dim3(16, 16, 1), blk512, 0, stream>>>(h1b, W1t, mid, b1,
        ROWS_, FFN_, D_, D_, D_, 0, 0, 0, 1.f);
    // 10-11. hf partials ; out = LN(h1 + sum + b2)
    {
        const int KC = FFN_ / SK;
        if (SK == 4) {
            gemm256<0><<<dim3(16, 4, 4), blk512, 0, stream>>>(mid, W2t, P, nullptr,
                ROWS_, D_, KC, FFN_, FFN_, KC, KC, (long)ROWS_ * D_, 1.f);
            layernorm_res2<4><<<ROWS_, blk, 0, stream>>>(P, b2, h1, g2, be2, (float*)d_out);
        } else if (SK == 2) {
            gemm256<0><<<dim3(16, 4, 2), blk512, 0, stream>>>(mid, W2t, P, nullptr,
                ROWS_, D_, KC, FFN_, FFN_, KC, KC, (long)ROWS_ * D_, 1.f);
            layernorm_res2<2><<<ROWS_, blk, 0, stream>>>(P, b2, h1, g2, be2, (float*)d_out);
        } else {
            gemm128<128, 0><<<dim3(32, 8, 1), blk, 0, stream>>>(mid, W2t, P, nullptr,
                ROWS_, D_, FFN_, FFN_, FFN_, 0, 0, 0, 1.f);
            layernorm_res2<1><<<ROWS_, blk, 0, stream>>>(P, b2, h1, g2, be2, (float*)d_out);
        }
    }
}

// Round 9
// 365.729 us; speedup vs baseline: 1.3028x; 1.0339x over previous
//
#include <hip/hip_runtime.h>

typedef __bf16 bf16;
typedef __bf16 bf16x8 __attribute__((ext_vector_type(8)));
typedef __bf16 bf16x4 __attribute__((ext_vector_type(4)));
typedef float  f32x4  __attribute__((ext_vector_type(4)));

#define D_     1024
#define FFN_   4096
#define NH_    8
#define HD_    128
#define L_     2048
#define B_     2
#define ROWS_  4096           // B_*L_
#define PAIRS_ 16             // B_*NH_
#define KT_    64             // flash K-tile (keys)
#define PSTR   72             // Ps row stride (bf16): 144 B = 16B-aligned rows
#define ALPHA_  0.08838834764831845f   // 1/sqrt(128)
#define RSCALE_ 5.656854249492381f     // 0.5/ALPHA_

// async 16B global -> LDS (wave-uniform LDS base + lane*16 implicit)
__device__ __forceinline__ void async16(const bf16* g, bf16* l) {
    __builtin_amdgcn_global_load_lds(
        (const __attribute__((address_space(1))) unsigned int*)g,
        (__attribute__((address_space(3))) unsigned int*)l, 16, 0, 0);
}
__device__ __forceinline__ f32x4 MFMA(bf16x8 a, bf16x8 b, f32x4 c) {
    return __builtin_amdgcn_mfma_f32_16x16x32_bf16(a, b, c, 0, 0, 0);
}

// ---------------- mega-prep: ONE dispatch for all preprocessing ----------------
// blocks [0,4096): h fp32 -> hb bf16
// blocks [4096,8192): Wq/Wk/Wv/Wo 1024x1024 transpose -> bf16 (1024 blocks each)
// blocks [8192,12288): W1 [D][FFN] -> W1t [FFN][D]
// blocks [12288,16384): W2 [FFN][D] -> W2t [D][FFN]
// blocks [16384,16400): rqk relevance projections
__global__ void prep_kernel(const float* __restrict__ h, bf16* __restrict__ hb,
                            const float* __restrict__ Wq, const float* __restrict__ Wk,
                            const float* __restrict__ Wv, const float* __restrict__ Wo,
                            bf16* __restrict__ Wqt, bf16* __restrict__ Wkt,
                            bf16* __restrict__ Wvt, bf16* __restrict__ Wot,
                            const float* __restrict__ W1, bf16* __restrict__ W1t,
                            const float* __restrict__ W2, bf16* __restrict__ W2t,
                            const float* __restrict__ rh, const float* __restrict__ Wrq,
                            const float* __restrict__ Wrk, float* __restrict__ rq,
                            float* __restrict__ rk) {
    __shared__ bf16 t[32][33];
    int bid = blockIdx.x;
    if (bid < 4096) {                      // ---- cvt h -> hb ----
        long i = ((long)bid * 256 + threadIdx.x) * 4;
        float4 v = *(const float4*)(h + i);
        bf16x4 o = {(bf16)v.x, (bf16)v.y, (bf16)v.z, (bf16)v.w};
        *(bf16x4*)(hb + i) = o;
        return;
    }
    bid -= 4096;
    if (bid >= 12288) {                    // ---- rqk (16 blocks) ----
        int tt = (bid - 12288) * 256 + threadIdx.x;
        float4 r = *(const float4*)(rh + (long)tt * 4);
        float q[4], k[4];
#pragma unroll
        for (int c = 0; c < 4; c++) {
            q[c] = r.x * Wrq[c] + r.y * Wrq[4 + c] + r.z * Wrq[8 + c] + r.w * Wrq[12 + c];
            k[c] = r.x * Wrk[c] + r.y * Wrk[4 + c] + r.z * Wrk[8 + c] + r.w * Wrk[12 + c];
        }
        float4 qo = {q[0], q[1], q[2], q[3]};
        float4 ko = {k[0], k[1], k[2], k[3]};
        *(float4*)(rq + (long)tt * 4) = qo;
        *(float4*)(rk + (long)tt * 4) = ko;
        return;
    }
    // ---- transposes (32x32 LDS tile, identical inner body to the verified kernel) ----
    const float* in; bf16* out; int r, c, x0, y0;
    if (bid < 4096) {                      // Wq/Wk/Wv/Wo: 1024 blocks each
        int m = bid >> 10, xy = bid & 1023;
        switch (m) { case 0: in = Wq; out = Wqt; break;
                     case 1: in = Wk; out = Wkt; break;
                     case 2: in = Wv; out = Wvt; break;
                     default: in = Wo; out = Wot; break; }
        r = D_; c = D_;
        x0 = (xy & 31) * 32; y0 = (xy >> 5) * 32;
    } else if (bid < 8192) {               // W1 [D][FFN] -> [FFN][D]; tiles x:128 y:32
        int xy = bid - 4096;
        in = W1; out = W1t; r = D_; c = FFN_;
        x0 = (xy & 127) * 32; y0 = (xy >> 7) * 32;
    } else {                               // W2 [FFN][D] -> [D][FFN]; tiles x:32 y:128
        int xy = bid - 8192;
        in = W2; out = W2t; r = FFN_; c = D_;
        x0 = (xy & 31) * 32; y0 = (xy >> 5) * 32;
    }
    int tx = threadIdx.x & 31, ty = threadIdx.x >> 5;  // 32 x 8
#pragma unroll
    for (int i = 0; i < 4; i++)
        t[ty + i * 8][tx] = (bf16)in[(long)(y0 + ty + i * 8) * c + x0 + tx];
    __syncthreads();
#pragma unroll
    for (int i = 0; i < 4; i++)
        out[(long)(x0 + ty + i * 8) * r + y0 + tx] = t[tx][ty + i * 8];
}

// ---------------- fused per-pair K and V transposes (one dispatch) ----------------
// blocks [0,4096): kT[m][d] from kb pair-chunk viewed [HD][L] (64x4 tiles/pair)
// blocks [4096,8192): vT[d][key] from vb pair-chunk viewed [L][HD] (4x64 tiles/pair)
__global__ void transposeKV(const bf16* __restrict__ kb, bf16* __restrict__ kTo,
                            const bf16* __restrict__ vb, bf16* __restrict__ vTo) {
    __shared__ bf16 t[32][33];
    int bid = blockIdx.x;
    const bf16* in; bf16* out; int r, c, x0, y0; long zoff;
    if (bid < 4096) {
        int z = bid >> 8, xy = bid & 255;   // 256 tiles/pair: x 64, y 4
        in = kb; out = kTo; r = HD_; c = L_;
        x0 = (xy & 63) * 32; y0 = (xy >> 6) * 32;
        zoff = (long)z * (L_ * HD_);
    } else {
        int b2 = bid - 4096;
        int z = b2 >> 8, xy = b2 & 255;     // 256 tiles/pair: x 4, y 64
        in = vb; out = vTo; r = L_; c = HD_;
        x0 = (xy & 3) * 32; y0 = (xy >> 2) * 32;
        zoff = (long)z * (L_ * HD_);
    }
    int tx = threadIdx.x & 31, ty = threadIdx.x >> 5;
#pragma unroll
    for (int i = 0; i < 4; i++)
        t[ty + i * 8][tx] = in[zoff + (long)(y0 + ty + i * 8) * c + x0 + tx];
    __syncthreads();
#pragma unroll
    for (int i = 0; i < 4; i++)
        out[zoff + (long)(x0 + ty + i * 8) * r + y0 + tx] = t[tx][ty + i * 8];
}

// ---------------- m97-style MFMA GEMM (Wo + fallback) ----------------
template<int BM, int EPI>
__launch_bounds__(256)
__global__ void gemm128(const bf16* __restrict__ A, const bf16* __restrict__ Bt,
                        void* __restrict__ Cv, const float* __restrict__ bias,
                        int M, int N, int K, int lda, int ldb,
                        long sA, long sB, long sC, float alpha) {
    constexpr int RF = (BM == 128) ? 4 : 2;
    __shared__ __align__(16) bf16 As[BM * 32];
    __shared__ __align__(16) bf16 Bs[128 * 32];
    const int tid  = threadIdx.x;
    const int wave = tid >> 6, lane = tid & 63;
    const int quad = lane >> 4, mr = lane & 15;
    const int bM = blockIdx.x * BM, bN = blockIdx.y * 128;
    A  += (long)blockIdx.z * sA;
    Bt += (long)blockIdx.z * sB;
    const int wr = (wave >> 1) * (BM / 2), wc = (wave & 1) * 64;

    f32x4 acc[RF][4];
#pragma unroll
    for (int r = 0; r < RF; r++)
#pragma unroll
        for (int c = 0; c < 4; c++) { f32x4 z = {0.f, 0.f, 0.f, 0.f}; acc[r][c] = z; }

    const int scol = (lane & 3) * 8;
    const bf16* Ag0; const bf16* Ag1 = nullptr;
    if (BM == 128) {
        const int srow = wave * 32 + (lane >> 2);
        Ag0 = A + (long)(bM + srow) * lda + scol;
        Ag1 = Ag0 + (long)16 * lda;
    } else {
        const int srow = wave * 16 + (lane >> 2);
        Ag0 = A + (long)(bM + srow) * lda + scol;
    }
    const int srowB = wave * 32 + (lane >> 2);
    const bf16* Bg0 = Bt + (long)(bN + srowB) * ldb + scol;
    const bf16* Bg1 = Bg0 + (long)16 * ldb;
    bf16* AsW = As + wave * (BM == 128 ? 1024 : 512);
    bf16* BsW = Bs + wave * 1024;

    for (int k0 = 0; k0 < K; k0 += 32) {
        if (BM == 128) { async16(Ag0, AsW); async16(Ag1, AsW + 512); Ag0 += 32; Ag1 += 32; }
        else           { async16(Ag0, AsW); Ag0 += 32; }
        async16(Bg0, BsW); async16(Bg1, BsW + 512);
        Bg0 += 32; Bg1 += 32;
        __syncthreads();
        bf16x8 af[RF], bfv[4];
#pragma unroll
        for (int r = 0; r < RF; r++)
            af[r] = *(const bf16x8*)(&As[(wr + r * 16 + mr) * 32 + quad * 8]);
#pragma unroll
        for (int c = 0; c < 4; c++)
            bfv[c] = *(const bf16x8*)(&Bs[(wc + c * 16 + mr) * 32 + quad * 8]);
#pragma unroll
        for (int r = 0; r < RF; r++)
#pragma unroll
            for (int c = 0; c < 4; c++)
                acc[r][c] = MFMA(af[r], bfv[c], acc[r][c]);
        __syncthreads();
    }

    const long zC = (long)blockIdx.z * sC;
    float bias_c[4];
    if (EPI & 1) {
#pragma unroll
        for (int c = 0; c < 4; c++) bias_c[c] = bias[bN + wc + c * 16 + mr];
    }
#pragma unroll
    for (int r = 0; r < RF; r++) {
#pragma unroll
        for (int c = 0; c < 4; c++) {
            const long col = bN + wc + c * 16 + mr;
#pragma unroll
            for (int i = 0; i < 4; i++) {
                const long row = bM + wr + r * 16 + quad * 4 + i;
                float v = acc[r][c][i] * alpha;
                if (EPI & 1) v += bias_c[c];
                if (EPI & 2) v = fmaxf(v, 0.f);
                if (EPI & 4) ((bf16*)Cv)[zC + row * (long)N + col] = (bf16)v;
                else         ((float*)Cv)[zC + row * (long)N + col] = v;
            }
        }
    }
}

// ---------------- 256x256 8-phase pipelined MFMA GEMM (T2+T3+T4+T5) ----------------
// Ring-4 LDS with counted vmcnt(8): ~3 K-tiles of prefetch cover.
template<int EPI>
__launch_bounds__(512, 2)
__global__ void gemm256(const bf16* __restrict__ A, const bf16* __restrict__ Bt,
                        void* __restrict__ Cv, const float* __restrict__ bias,
                        int M, int N, int K, int lda, int ldb,
                        long sA, long sB, long sC, float alpha) {
    __shared__ __align__(16) bf16 LA[4][256 * 32];   // 4 x 16 KB
    __shared__ __align__(16) bf16 LB[4][256 * 32];   // 4 x 16 KB
    const int tid = threadIdx.x, wave = tid >> 6, lane = tid & 63;
    const int quad = lane >> 4, mr = lane & 15;
    const int wr = wave >> 2, wc = wave & 3;
    const int bM = blockIdx.x * 256, bN = blockIdx.y * 256;
    (void)M;
    A  += (long)blockIdx.z * sA;
    Bt += (long)blockIdx.z * sB;

    const int srow = tid >> 2;
    const int sg   = (((tid & 3) ^ ((tid >> 3) & 3))) * 8;
    const bf16* Ag = A  + (long)(bM + srow) * lda + sg;
    const bf16* Bg = Bt + (long)(bN + srow) * ldb + sg;

    auto stageA = [&](int slot, int kt) {
        const bf16* s = Ag + kt * 32;
        async16(s,                   &LA[slot][wave * 512]);
        async16(s + (long)128 * lda, &LA[slot][4096 + wave * 512]);
    };
    auto stageB = [&](int slot, int kt) {
        const bf16* s = Bg + kt * 32;
        async16(s,                   &LB[slot][wave * 512]);
        async16(s + (long)128 * ldb, &LB[slot][4096 + wave * 512]);
    };

    f32x4 acc[8][4];
#pragma unroll
    for (int f = 0; f < 8; f++)
#pragma unroll
        for (int n = 0; n < 4; n++) { f32x4 z = {0.f, 0.f, 0.f, 0.f}; acc[f][n] = z; }

    const int gsw = (quad ^ ((mr >> 1) & 3)) * 8;

    stageA(0, 0); stageB(0, 0);
    stageA(1, 1); stageB(1, 1);
    stageA(2, 2); stageB(2, 2);
    asm volatile("s_waitcnt vmcnt(8)" ::: "memory");
    __builtin_amdgcn_s_barrier();

    const int NT = K >> 5;
    for (int t = 0; t < NT; ++t) {
        const int slot = t & 3;
        const bf16* As = &LA[slot][0];
        const bf16* Bs = &LB[slot][0];

        bf16x8 a0[4], bb[4];
#pragma unroll
        for (int f = 0; f < 4; f++)
            a0[f] = *(const bf16x8*)(As + (wr * 128 + f * 16 + mr) * 32 + gsw);
#pragma unroll
        for (int n = 0; n < 4; n++)
            bb[n] = *(const bf16x8*)(Bs + (wc * 64 + n * 16 + mr) * 32 + gsw);
        if (t + 3 < NT) stageA((t + 3) & 3, t + 3);
        __builtin_amdgcn_s_barrier();
        asm volatile("s_waitcnt lgkmcnt(0)" ::: "memory");
        __builtin_amdgcn_sched_barrier(0);
        __builtin_amdgcn_s_setprio(1);
#pragma unroll
        for (int f = 0; f < 4; f++)
#pragma unroll
            for (int n = 0; n < 4; n++)
                acc[f][n] = MFMA(a0[f], bb[n], acc[f][n]);
        __builtin_amdgcn_s_setprio(0);
        __builtin_amdgcn_s_barrier();

        bf16x8 a1[4];
#pragma unroll
        for (int f = 0; f < 4; f++)
            a1[f] = *(const bf16x8*)(As + (wr * 128 + 64 + f * 16 + mr) * 32 + gsw);
        if (t + 3 < NT) stageB((t + 3) & 3, t + 3);
        __builtin_amdgcn_s_barrier();
        asm volatile("s_waitcnt lgkmcnt(0)" ::: "memory");
        __builtin_amdgcn_sched_barrier(0);
        __builtin_amdgcn_s_setprio(1);
#pragma unroll
        for (int f = 0; f < 4; f++)
#pragma unroll
            for (int n = 0; n < 4; n++)
                acc[4 + f][n] = MFMA(a1[f], bb[n], acc[4 + f][n]);
        __builtin_amdgcn_s_setprio(0);
        if (t < NT - 3)       asm volatile("s_waitcnt vmcnt(8)" ::: "memory");
        else if (t == NT - 3) asm volatile("s_waitcnt vmcnt(4)" ::: "memory");
        else if (t == NT - 2) asm volatile("s_waitcnt vmcnt(0)" ::: "memory");
        __builtin_amdgcn_s_barrier();
    }

    const long zC = (long)blockIdx.z * sC;
    float bias_c[4];
    if (EPI & 1) {
#pragma unroll
        for (int n = 0; n < 4; n++) bias_c[n] = bias[bN + wc * 64 + n * 16 + mr];
    }
#pragma unroll
    for (int f = 0; f < 8; f++) {
#pragma unroll
        for (int n = 0; n < 4; n++) {
            const long col = bN + wc * 64 + n * 16 + mr;
#pragma unroll
            for (int i = 0; i < 4; i++) {
                const long row = bM + wr * 128 + f * 16 + quad * 4 + i;
                float v = acc[f][n][i] * alpha;
                if (EPI & 1) v += bias_c[n];
                if (EPI & 2) v = fmaxf(v, 0.f);
                if (EPI & 4) ((bf16*)Cv)[zC + row * (long)N + col] = (bf16)v;
                else         ((float*)Cv)[zC + row * (long)N + col] = v;
            }
        }
    }
}

// ---------------- fused flash attention with relevance bias, K-split ----------------
// Round-3/4 proven body (4 waves, 128-row Q-tile, single-buffered 2-barrier loop,
// 51 KB LDS) + T1 bijective XCD chunking (FETCH 74->17 MB verified) + T5 setprio.
template<int SPLIT>
__launch_bounds__(256, 1)
__global__ void flash_attn(const bf16* __restrict__ qb, const bf16* __restrict__ kT,
                           const bf16* __restrict__ vT, const float* __restrict__ rq,
                           const float* __restrict__ rk, bf16* __restrict__ ctx,
                           float* __restrict__ opart, float* __restrict__ osum) {
    __shared__ __align__(16) bf16  Ksh[KT_ * HD_];   // [key][d], granule-swizzled
    __shared__ __align__(16) bf16  Vsh[HD_ * KT_];   // [d][key], granule-swizzled
    __shared__ __align__(16) float rks[4 * KT_];     // [r][key] fp32
    __shared__ __align__(16) bf16  Ps[4][32 * PSTR]; // per-wave P, 16B-aligned rows

    const int tid = threadIdx.x, wave = tid >> 6, lane = tid & 63;
    const int quad = lane >> 4, mr = lane & 15;
    // T1: bijective XCD chunking. grid (16,16,SPLIT) -> nwg = 256*SPLIT (div by 8).
    const int nwg = 256 * SPLIT;
    const int lid = blockIdx.x + (blockIdx.y << 4) + (blockIdx.z << 8);
    const int wid = (lid & 7) * (nwg >> 3) + (lid >> 3);
    const int ksp = wid >> 8;
    const int pair = (wid >> 4) & 15, b = pair >> 3;
    const int bQ = (wid & 15) * 128;
    const long PB = (long)pair * L_ * HD_;
    const bf16* Qg = qb + PB;
    const bf16* Kg = kT + PB;
    const bf16* Vg = vT + PB;
    const float* rkb = rk + (long)b * L_ * 4;

    // Q fragments in registers (A-layout): rows bQ + wave*32 + f*16 + mr
    bf16x8 Qf[2][4], Qe[2];
#pragma unroll
    for (int f = 0; f < 2; f++) {
#pragma unroll
        for (int t = 0; t < 4; t++)
            Qf[f][t] = *(const bf16x8*)(Qg + (long)(bQ + wave * 32 + f * 16 + mr) * HD_ + t * 32 + quad * 8);
        bf16x8 z = {};
        if (quad == 0) {
            float4 v = *(const float4*)(rq + ((long)b * L_ + bQ + wave * 32 + f * 16 + mr) * 4);
            z[0] = (bf16)(v.x * RSCALE_); z[1] = (bf16)(v.y * RSCALE_);
            z[2] = (bf16)(v.z * RSCALE_); z[3] = (bf16)(v.w * RSCALE_);
        }
        Qe[f] = z;
    }

    bf16x8 ones;
#pragma unroll
    for (int j = 0; j < 8; j++) ones[j] = (bf16)1.0f;

    f32x4 O[2][8], Os[2];
#pragma unroll
    for (int f = 0; f < 2; f++) {
#pragma unroll
        for (int c = 0; c < 8; c++) { f32x4 z = {0.f, 0.f, 0.f, 0.f}; O[f][c] = z; }
        f32x4 z = {0.f, 0.f, 0.f, 0.f}; Os[f] = z;
    }

    const int tile0 = ksp * ((L_ / KT_) / SPLIT);
    const int tile1 = tile0 + (L_ / KT_) / SPLIT;
    for (int kt = tile0; kt < tile1; kt++) {
        const int kt0 = kt * KT_;
        // ---- stage K/V/rk (single buffer) ----
#pragma unroll
        for (int it = 0; it < 4; it++) {
            int G = it * 256 + tid;
            int r1 = G >> 4, g1 = (G & 15) ^ (r1 & 15);
            async16(Kg + (long)(kt0 + r1) * HD_ + g1 * 8, &Ksh[(it * 256 + wave * 64) * 8]);
            int r2 = G >> 3, g2 = (G & 7) ^ (r2 & 7);
            async16(Vg + (long)r2 * L_ + kt0 + g2 * 8, &Vsh[(it * 256 + wave * 64) * 8]);
        }
        if (tid < 64) {
            int r3 = tid >> 4, g3 = tid & 15;
            async16((const bf16*)(rkb + (long)r3 * L_ + kt0 + g3 * 4), (bf16*)&rks[0]);
        }
        __syncthreads();   // drains vmcnt -> LDS valid for all waves

        bf16* PsW = Ps[wave];

        // ---- S = Q K^T (+ ext bias chunk), 4 col-blocks of 16 keys ----
        f32x4 sc[4][2];
        __builtin_amdgcn_s_setprio(1);
#pragma unroll
        for (int c = 0; c < 4; c++) {
            f32x4 s0 = {0.f, 0.f, 0.f, 0.f}, s1 = s0;
#pragma unroll
            for (int t = 0; t < 4; t++) {
                bf16x8 kf = *(const bf16x8*)(Ksh + (c * 16 + mr) * HD_ + (((t * 4 + quad) ^ mr) * 8));
                s0 = MFMA(Qf[0][t], kf, s0);
                s1 = MFMA(Qf[1][t], kf, s1);
            }
            bf16x8 ke = {};
            if (quad == 0) {
                ke[0] = (bf16)rks[0 * KT_ + c * 16 + mr];
                ke[1] = (bf16)rks[1 * KT_ + c * 16 + mr];
                ke[2] = (bf16)rks[2 * KT_ + c * 16 + mr];
                ke[3] = (bf16)rks[3 * KT_ + c * 16 + mr];
            }
            s0 = MFMA(Qe[0], ke, s0);
            s1 = MFMA(Qe[1], ke, s1);
            sc[c][0] = s0; sc[c][1] = s1;
        }
        __builtin_amdgcn_s_setprio(0);

        // ---- P = exp(ALPHA*S) straight to LDS (no max, no shuffles) ----
#pragma unroll
        for (int f = 0; f < 2; f++) {
#pragma unroll
            for (int i = 0; i < 4; i++) {
                const int prow = (f * 16 + quad * 4 + i) * PSTR;
                PsW[prow + 0 * 16 + mr] = (bf16)__expf(sc[0][f][i] * ALPHA_);
                PsW[prow + 1 * 16 + mr] = (bf16)__expf(sc[1][f][i] * ALPHA_);
                PsW[prow + 2 * 16 + mr] = (bf16)__expf(sc[2][f][i] * ALPHA_);
                PsW[prow + 3 * 16 + mr] = (bf16)__expf(sc[3][f][i] * ALPHA_);
            }
        }

        // ---- O += P @ V ; Os += P @ ones (row sums) ----
        __builtin_amdgcn_s_setprio(1);
#pragma unroll
        for (int t = 0; t < 2; t++) {
            bf16x8 pf0 = *(const bf16x8*)(PsW + (0 * 16 + mr) * PSTR + t * 32 + quad * 8);
            bf16x8 pf1 = *(const bf16x8*)(PsW + (1 * 16 + mr) * PSTR + t * 32 + quad * 8);
            Os[0] = MFMA(pf0, ones, Os[0]);
            Os[1] = MFMA(pf1, ones, Os[1]);
#pragma unroll
            for (int c2 = 0; c2 < 8; c2++) {
                bf16x8 vf = *(const bf16x8*)(Vsh + (c2 * 16 + mr) * KT_ + (((t * 4 + quad) ^ (mr & 7)) * 8));
                O[0][c2] = MFMA(pf0, vf, O[0][c2]);
                O[1][c2] = MFMA(pf1, vf, O[1][c2]);
            }
        }
        __builtin_amdgcn_s_setprio(0);
        __syncthreads();   // all waves done reading K/V before restage
    }

    // ---- epilogue ----
    if (SPLIT == 1) {
        bf16* Cg = ctx + PB;
#pragma unroll
        for (int f = 0; f < 2; f++)
#pragma unroll
            for (int i = 0; i < 4; i++) {
                const float inv = 1.f / Os[f][i];
                const long row = bQ + wave * 32 + f * 16 + quad * 4 + i;
#pragma unroll
                for (int c2 = 0; c2 < 8; c2++)
                    Cg[row * HD_ + c2 * 16 + mr] = (bf16)(O[f][c2][i] * inv);
            }
    } else {
        float* Og = opart + (long)ksp * ((long)PAIRS_ * L_ * HD_) + PB;
        float* Sg = osum + (long)ksp * (PAIRS_ * L_) + pair * L_;
#pragma unroll
        for (int f = 0; f < 2; f++)
#pragma unroll
            for (int i = 0; i < 4; i++) {
                const long row = bQ + wave * 32 + f * 16 + quad * 4 + i;
#pragma unroll
                for (int c2 = 0; c2 < 8; c2++)
                    Og[row * HD_ + c2 * 16 + mr] = O[f][c2][i];
                if (mr == 0) Sg[row] = Os[f][i];
            }
    }
}

// --------- combine KS flash partials: ctx = (sum O_z) / (sum s_z) ----------
template<int KS>
__global__ void flash_reduce(const float* __restrict__ op, const float* __restrict__ os,
                             bf16* __restrict__ ctx) {
    const long PLHD = (long)PAIRS_ * L_ * HD_;
    long e = ((long)blockIdx.x * 256 + threadIdx.x) * 4;
    long row = e >> 7;                       // / HD_
    float4 a = *(const float4*)(op + e);
    float s = os[row];
#pragma unroll
    for (int z = 1; z < KS; z++) {
        float4 p = *(const float4*)(op + (long)z * PLHD + e);
        a.x += p.x; a.y += p.y; a.z += p.z; a.w += p.w;
        s += os[(long)z * PAIRS_ * L_ + row];
    }
    float inv = 1.f / s;
    bf16x4 o = {(bf16)(a.x * inv), (bf16)(a.y * inv),
                (bf16)(a.z * inv), (bf16)(a.w * inv)};
    *(bf16x4*)(ctx + e) = o;
}

// ---------------- LN1: layernorm(x1 + x2) * g + be ; fp32 + bf16 out ----------------
__global__ void layernorm_res(const float* __restrict__ x1, const float* __restrict__ x2,
                              const float* __restrict__ g, const float* __restrict__ be,
                              float* __restrict__ outf, bf16* __restrict__ outb) {
    const int row = blockIdx.x, tid = threadIdx.x;
    const long base = (long)row * D_ + tid * 4;
    float4 a = *(const float4*)(x1 + base);
    float4 b = *(const float4*)(x2 + base);
    float x[4] = {a.x + b.x, a.y + b.y, a.z + b.z, a.w + b.w};
    float s = x[0] + x[1] + x[2] + x[3];
    float s2 = x[0] * x[0] + x[1] * x[1] + x[2] * x[2] + x[3] * x[3];
#pragma unroll
    for (int off = 32; off; off >>= 1) { s += __shfl_xor(s, off, 64); s2 += __shfl_xor(s2, off, 64); }
    __shared__ float ps[4], ps2[4];
    int wave = tid >> 6, lane = tid & 63;
    if (lane == 0) { ps[wave] = s; ps2[wave] = s2; }
    __syncthreads();
    s  = ps[0] + ps[1] + ps[2] + ps[3];
    s2 = ps2[0] + ps2[1] + ps2[2] + ps2[3];
    float mean = s * (1.f / D_);
    float var  = s2 * (1.f / D_) - mean * mean;
    float rstd = rsqrtf(var + 1e-5f);
    float4 gg = *(const float4*)(g + tid * 4);
    float4 bb = *(const float4*)(be + tid * 4);
    float y0 = (x[0] - mean) * rstd * gg.x + bb.x;
    float y1 = (x[1] - mean) * rstd * gg.y + bb.y;
    float y2 = (x[2] - mean) * rstd * gg.z + bb.z;
    float y3 = (x[3] - mean) * rstd * gg.w + bb.w;
    float4 yo = {y0, y1, y2, y3};
    *(float4*)(outf + base) = yo;
    bf16x4 ob = {(bf16)y0, (bf16)y1, (bf16)y2, (bf16)y3};
    *(bf16x4*)(outb + base) = ob;
}

// ---------------- LN2: layernorm(sum_z parts[z] + b2 + h1) * g + be -> fp32 ----------
template<int SK>
__global__ void layernorm_res2(const float* __restrict__ parts, const float* __restrict__ b2,
                               const float* __restrict__ x2, const float* __restrict__ g,
                               const float* __restrict__ be, float* __restrict__ outf) {
    const int row = blockIdx.x, tid = threadIdx.x;
    const long base = (long)row * D_ + tid * 4;
    float4 a = *(const float4*)(parts + base);
#pragma unroll
    for (int z = 1; z < SK; z++) {
        float4 p = *(const float4*)(parts + (long)z * ROWS_ * D_ + base);
        a.x += p.x; a.y += p.y; a.z += p.z; a.w += p.w;
    }
    float4 bb2 = *(const float4*)(b2 + tid * 4);
    float4 b = *(const float4*)(x2 + base);
    float x[4] = {a.x + bb2.x + b.x, a.y + bb2.y + b.y, a.z + bb2.z + b.z, a.w + bb2.w + b.w};
    float s = x[0] + x[1] + x[2] + x[3];
    float s2 = x[0] * x[0] + x[1] * x[1] + x[2] * x[2] + x[3] * x[3];
#pragma unroll
    for (int off = 32; off; off >>= 1) { s += __shfl_xor(s, off, 64); s2 += __shfl_xor(s2, off, 64); }
    __shared__ float ps[4], ps2[4];
    int wave = tid >> 6, lane = tid & 63;
    if (lane == 0) { ps[wave] = s; ps2[wave] = s2; }
    __syncthreads();
    s  = ps[0] + ps[1] + ps[2] + ps[3];
    s2 = ps2[0] + ps2[1] + ps2[2] + ps2[3];
    float mean = s * (1.f / D_);
    float var  = s2 * (1.f / D_) - mean * mean;
    float rstd = rsqrtf(var + 1e-5f);
    float4 gg = *(const float4*)(g + tid * 4);
    float4 bb = *(const float4*)(be + tid * 4);
    float4 yo = {(x[0] - mean) * rstd * gg.x + bb.x, (x[1] - mean) * rstd * gg.y + bb.y,
                 (x[2] - mean) * rstd * gg.z + bb.z, (x[3] - mean) * rstd * gg.w + bb.w};
    *(float4*)(outf + base) = yo;
}

// ---------------- launch ----------------
extern "C" void kernel_launch(void* const* d_in, const int* in_sizes, int n_in,
                              void* d_out, int out_size, void* d_ws, size_t ws_size,
                              hipStream_t stream) {
    (void)in_sizes; (void)n_in; (void)out_size;
    const float* h   = (const float*)d_in[0];
    const float* rh  = (const float*)d_in[1];
    const float* Wq  = (const float*)d_in[2];
    const float* Wk  = (const float*)d_in[3];
    const float* Wv  = (const float*)d_in[4];
    const float* Wo  = (const float*)d_in[5];
    const float* Wrk = (const float*)d_in[6];
    const float* Wrq = (const float*)d_in[7];
    const float* W1  = (const float*)d_in[8];
    const float* b1  = (const float*)d_in[9];
    const float* W2  = (const float*)d_in[10];
    const float* b2  = (const float*)d_in[11];
    const float* g1  = (const float*)d_in[12];
    const float* be1 = (const float*)d_in[13];
    const float* g2  = (const float*)d_in[14];
    const float* be2 = (const float*)d_in[15];

    char* w = (char*)d_ws;
    size_t used = 0;
    auto alloc = [&](size_t bytes) { char* p = w + used; used += (bytes + 255) & ~(size_t)255; return p; };
    bf16*  hb   = (bf16*)alloc((size_t)ROWS_ * D_ * 2);       // 8 MB; later ctx, then h1b
    bf16*  Wqt  = (bf16*)alloc((size_t)D_ * D_ * 2);          // Wqt/Wkt/Wvt contiguous (z-batch)
    bf16*  Wkt  = (bf16*)alloc((size_t)D_ * D_ * 2);
    bf16*  Wvt  = (bf16*)alloc((size_t)D_ * D_ * 2);
    bf16*  Wot  = (bf16*)alloc((size_t)D_ * D_ * 2);
    bf16*  W1t  = (bf16*)alloc((size_t)D_ * FFN_ * 2);
    bf16*  W2t  = (bf16*)alloc((size_t)FFN_ * D_ * 2);
    bf16*  qb   = (bf16*)alloc((size_t)ROWS_ * D_ * 2);       // qb/kb/vb contiguous (z-batch out)
    bf16*  kb   = (bf16*)alloc((size_t)ROWS_ * D_ * 2);
    bf16*  vb   = (bf16*)alloc((size_t)ROWS_ * D_ * 2);
    bf16*  kT   = (bf16*)alloc((size_t)ROWS_ * D_ * 2);       // kT[m][d] = chunk[d*L+m]
    bf16*  vT   = (bf16*)alloc((size_t)ROWS_ * D_ * 2);       // vT[d][key]
    float* rq   = (float*)alloc((size_t)ROWS_ * 4 * 4);
    float* rk   = (float*)alloc((size_t)ROWS_ * 4 * 4);
    float* h1   = (float*)alloc((size_t)ROWS_ * D_ * 4);      // 16 MB, live to the end

    // ---- shared scratch region: flash K-split partials, then hsa, then FFN2 partials
    const size_t psz    = (size_t)ROWS_ * D_ * 4;             // 16 MB
    const size_t PLHD   = (size_t)PAIRS_ * L_ * HD_;          // elements
    const size_t needKS = 2 * PLHD * 4 + 2 * (size_t)PAIRS_ * L_ * 4;  // ~32.25 MB
    const size_t avail  = (ws_size > used) ? ws_size - used : 0;
    const int SK = (avail >= 4 * psz) ? 4 : (avail >= 2 * psz) ? 2 : 1;
    size_t region = (size_t)SK * psz;
    const int KS = (avail >= (needKS > region ? needKS : region)) ? 2 : 1;
    if (KS == 2 && needKS > region) region = needKS;
    float* P = (float*)alloc(region);
    float* hsa   = P;
    float* Opart = P;
    float* Osum  = P + 2 * PLHD;
    bf16* ctx = hb;
    bf16* mid = qb;    // 32 MB over qb..kT, live after flash
    bf16* h1b = hb;    // over hb, live after Wo

    const dim3 blk(256);
    const dim3 blk512(512);

    // 1. ALL preprocessing in one dispatch: cvt + 6 weight transposes + rqk
    prep_kernel<<<16400, blk, 0, stream>>>(h, hb, Wq, Wk, Wv, Wo, Wqt, Wkt, Wvt, Wot,
                                           W1, W1t, W2, W2t, rh, Wrq, Wrk, rq, rk);
    // 2. QKV projections, z=3 batched (192 blocks, 256^2 ring-4)
    gemm256<4><<<dim3(16, 4, 3), blk512, 0, stream>>>(hb, Wqt, qb, nullptr,
        ROWS_, D_, D_, D_, D_, 0, (long)D_ * D_, (long)ROWS_ * D_, 1.f);
    // 3. per-(b,n) K and V transposes in one dispatch
    transposeKV<<<8192, blk, 0, stream>>>(kb, kT, vb, vT);
    // 4. fused flash attention -> ctx (K-split 2 when workspace allows)
    if (KS == 2) {
        flash_attn<2><<<dim3(16, 16, 2), blk, 0, stream>>>(qb, kT, vT, rq, rk, ctx, Opart, Osum);
        flash_reduce<2><<<PAIRS_ * L_ * HD_ / 1024, blk, 0, stream>>>(Opart, Osum, ctx);
    } else {
        flash_attn<1><<<dim3(16, 16, 1), blk, 0, stream>>>(qb, kT, vT, rq, rk, ctx, Opart, Osum);
    }
    // 5. h_sa = ctx @ Wo (fp32)
    gemm128<64, 0><<<dim3(64, 8, 1), blk, 0, stream>>>(ctx, Wot, hsa, nullptr,
        ROWS_, D_, D_, D_, D_, 0, 0, 0, 1.f);
    // 6. h1 = LN(h_sa + h)
    layernorm_res<<<ROWS_, blk, 0, stream>>>(hsa, h, g1, be1, h1, h1b);
    // 7. mid = relu(h1 @ W1 + b1)  (256 blocks, 256^2 ring-4)
    gemm256<7><<<dim3(16, 16, 1), blk512, 0, stream>>>(h1b, W1t, mid, b1,
        ROWS_, FFN_, D_, D_, D_, 0, 0, 0, 1.f);
    // 8-9. hf partials ; out = LN(h1 + sum + b2)
    {
        const int KC = FFN_ / SK;
        if (SK == 4) {
            gemm256<0><<<dim3(16, 4, 4), blk512, 0, stream>>>(mid, W2t, P, nullptr,
                ROWS_, D_, KC, FFN_, FFN_, KC, KC, (long)ROWS_ * D_, 1.f);
            layernorm_res2<4><<<ROWS_, blk, 0, stream>>>(P, b2, h1, g2, be2, (float*)d_out);
        } else if (SK == 2) {
            gemm256<0><<<dim3(16, 4, 2), blk512, 0, stream>>>(mid, W2t, P, nullptr,
                ROWS_, D_, KC, FFN_, FFN_, KC, KC, (long)ROWS_ * D_, 1.f);
            layernorm_res2<2><<<ROWS_, blk, 0, stream>>>(P, b2, h1, g2, be2, (float*)d_out);
        } else {
            gemm128<128, 0><<<dim3(32, 8, 1), blk, 0, stream>>>(mid, W2t, P, nullptr,
                ROWS_, D_, FFN_, FFN_, FFN_, 0, 0, 0, 1.f);
            layernorm_res2<1><<<ROWS_, blk, 0, stream>>>(P, b2, h1, g2, be2, (float*)d_out);
        }
    }
}

// Round 10
// 363.526 us; speedup vs baseline: 1.3107x; 1.0061x over previous
//
#include <hip/hip_runtime.h>

typedef __bf16 bf16;
typedef __bf16 bf16x8 __attribute__((ext_vector_type(8)));
typedef __bf16 bf16x4 __attribute__((ext_vector_type(4)));
typedef float  f32x4  __attribute__((ext_vector_type(4)));

#define D_     1024
#define FFN_   4096
#define NH_    8
#define HD_    128
#define L_     2048
#define B_     2
#define ROWS_  4096           // B_*L_
#define PAIRS_ 16             // B_*NH_
#define KT_    64             // flash K-tile (keys)
#define PSTR   72             // Ps row stride (bf16): 144 B = 16B-aligned rows
#define ALPHA_  0.08838834764831845f   // 1/sqrt(128)
#define EXP2S_  0.1275174315f          // ALPHA_ * log2(e): exp(s*ALPHA) = exp2(s*EXP2S)
#define RSCALE_ 5.656854249492381f     // 0.5/ALPHA_

// async 16B global -> LDS (wave-uniform LDS base + lane*16 implicit)
__device__ __forceinline__ void async16(const bf16* g, bf16* l) {
    __builtin_amdgcn_global_load_lds(
        (const __attribute__((address_space(1))) unsigned int*)g,
        (__attribute__((address_space(3))) unsigned int*)l, 16, 0, 0);
}
__device__ __forceinline__ f32x4 MFMA(bf16x8 a, bf16x8 b, f32x4 c) {
    return __builtin_amdgcn_mfma_f32_16x16x32_bf16(a, b, c, 0, 0, 0);
}

// ---------------- mega-prep: ONE dispatch for all preprocessing ----------------
__global__ void prep_kernel(const float* __restrict__ h, bf16* __restrict__ hb,
                            const float* __restrict__ Wq, const float* __restrict__ Wk,
                            const float* __restrict__ Wv, const float* __restrict__ Wo,
                            bf16* __restrict__ Wqt, bf16* __restrict__ Wkt,
                            bf16* __restrict__ Wvt, bf16* __restrict__ Wot,
                            const float* __restrict__ W1, bf16* __restrict__ W1t,
                            const float* __restrict__ W2, bf16* __restrict__ W2t,
                            const float* __restrict__ rh, const float* __restrict__ Wrq,
                            const float* __restrict__ Wrk, float* __restrict__ rq,
                            float* __restrict__ rk) {
    __shared__ bf16 t[32][33];
    int bid = blockIdx.x;
    if (bid < 4096) {                      // ---- cvt h -> hb ----
        long i = ((long)bid * 256 + threadIdx.x) * 4;
        float4 v = *(const float4*)(h + i);
        bf16x4 o = {(bf16)v.x, (bf16)v.y, (bf16)v.z, (bf16)v.w};
        *(bf16x4*)(hb + i) = o;
        return;
    }
    bid -= 4096;
    if (bid >= 12288) {                    // ---- rqk (16 blocks) ----
        int tt = (bid - 12288) * 256 + threadIdx.x;
        float4 r = *(const float4*)(rh + (long)tt * 4);
        float q[4], k[4];
#pragma unroll
        for (int c = 0; c < 4; c++) {
            q[c] = r.x * Wrq[c] + r.y * Wrq[4 + c] + r.z * Wrq[8 + c] + r.w * Wrq[12 + c];
            k[c] = r.x * Wrk[c] + r.y * Wrk[4 + c] + r.z * Wrk[8 + c] + r.w * Wrk[12 + c];
        }
        float4 qo = {q[0], q[1], q[2], q[3]};
        float4 ko = {k[0], k[1], k[2], k[3]};
        *(float4*)(rq + (long)tt * 4) = qo;
        *(float4*)(rk + (long)tt * 4) = ko;
        return;
    }
    const float* in; bf16* out; int r, c, x0, y0;
    if (bid < 4096) {                      // Wq/Wk/Wv/Wo: 1024 blocks each
        int m = bid >> 10, xy = bid & 1023;
        switch (m) { case 0: in = Wq; out = Wqt; break;
                     case 1: in = Wk; out = Wkt; break;
                     case 2: in = Wv; out = Wvt; break;
                     default: in = Wo; out = Wot; break; }
        r = D_; c = D_;
        x0 = (xy & 31) * 32; y0 = (xy >> 5) * 32;
    } else if (bid < 8192) {               // W1 [D][FFN] -> [FFN][D]
        int xy = bid - 4096;
        in = W1; out = W1t; r = D_; c = FFN_;
        x0 = (xy & 127) * 32; y0 = (xy >> 7) * 32;
    } else {                               // W2 [FFN][D] -> [D][FFN]
        int xy = bid - 8192;
        in = W2; out = W2t; r = FFN_; c = D_;
        x0 = (xy & 31) * 32; y0 = (xy >> 5) * 32;
    }
    int tx = threadIdx.x & 31, ty = threadIdx.x >> 5;  // 32 x 8
#pragma unroll
    for (int i = 0; i < 4; i++)
        t[ty + i * 8][tx] = (bf16)in[(long)(y0 + ty + i * 8) * c + x0 + tx];
    __syncthreads();
#pragma unroll
    for (int i = 0; i < 4; i++)
        out[(long)(x0 + ty + i * 8) * r + y0 + tx] = t[tx][ty + i * 8];
}

// ---------------- fused per-pair K and V transposes (one dispatch) ----------------
__global__ void transposeKV(const bf16* __restrict__ kb, bf16* __restrict__ kTo,
                            const bf16* __restrict__ vb, bf16* __restrict__ vTo) {
    __shared__ bf16 t[32][33];
    int bid = blockIdx.x;
    const bf16* in; bf16* out; int r, c, x0, y0; long zoff;
    if (bid < 4096) {
        int z = bid >> 8, xy = bid & 255;   // 256 tiles/pair: x 64, y 4
        in = kb; out = kTo; r = HD_; c = L_;
        x0 = (xy & 63) * 32; y0 = (xy >> 6) * 32;
        zoff = (long)z * (L_ * HD_);
    } else {
        int b2 = bid - 4096;
        int z = b2 >> 8, xy = b2 & 255;     // 256 tiles/pair: x 4, y 64
        in = vb; out = vTo; r = L_; c = HD_;
        x0 = (xy & 3) * 32; y0 = (xy >> 2) * 32;
        zoff = (long)z * (L_ * HD_);
    }
    int tx = threadIdx.x & 31, ty = threadIdx.x >> 5;
#pragma unroll
    for (int i = 0; i < 4; i++)
        t[ty + i * 8][tx] = in[zoff + (long)(y0 + ty + i * 8) * c + x0 + tx];
    __syncthreads();
#pragma unroll
    for (int i = 0; i < 4; i++)
        out[zoff + (long)(x0 + ty + i * 8) * r + y0 + tx] = t[tx][ty + i * 8];
}

// ---------------- m97-style MFMA GEMM (Wo + fallback) ----------------
template<int BM, int EPI>
__launch_bounds__(256)
__global__ void gemm128(const bf16* __restrict__ A, const bf16* __restrict__ Bt,
                        void* __restrict__ Cv, const float* __restrict__ bias,
                        int M, int N, int K, int lda, int ldb,
                        long sA, long sB, long sC, float alpha) {
    constexpr int RF = (BM == 128) ? 4 : 2;
    __shared__ __align__(16) bf16 As[BM * 32];
    __shared__ __align__(16) bf16 Bs[128 * 32];
    const int tid  = threadIdx.x;
    const int wave = tid >> 6, lane = tid & 63;
    const int quad = lane >> 4, mr = lane & 15;
    const int bM = blockIdx.x * BM, bN = blockIdx.y * 128;
    A  += (long)blockIdx.z * sA;
    Bt += (long)blockIdx.z * sB;
    const int wr = (wave >> 1) * (BM / 2), wc = (wave & 1) * 64;

    f32x4 acc[RF][4];
#pragma unroll
    for (int r = 0; r < RF; r++)
#pragma unroll
        for (int c = 0; c < 4; c++) { f32x4 z = {0.f, 0.f, 0.f, 0.f}; acc[r][c] = z; }

    const int scol = (lane & 3) * 8;
    const bf16* Ag0; const bf16* Ag1 = nullptr;
    if (BM == 128) {
        const int srow = wave * 32 + (lane >> 2);
        Ag0 = A + (long)(bM + srow) * lda + scol;
        Ag1 = Ag0 + (long)16 * lda;
    } else {
        const int srow = wave * 16 + (lane >> 2);
        Ag0 = A + (long)(bM + srow) * lda + scol;
    }
    const int srowB = wave * 32 + (lane >> 2);
    const bf16* Bg0 = Bt + (long)(bN + srowB) * ldb + scol;
    const bf16* Bg1 = Bg0 + (long)16 * ldb;
    bf16* AsW = As + wave * (BM == 128 ? 1024 : 512);
    bf16* BsW = Bs + wave * 1024;

    for (int k0 = 0; k0 < K; k0 += 32) {
        if (BM == 128) { async16(Ag0, AsW); async16(Ag1, AsW + 512); Ag0 += 32; Ag1 += 32; }
        else           { async16(Ag0, AsW); Ag0 += 32; }
        async16(Bg0, BsW); async16(Bg1, BsW + 512);
        Bg0 += 32; Bg1 += 32;
        __syncthreads();
        bf16x8 af[RF], bfv[4];
#pragma unroll
        for (int r = 0; r < RF; r++)
            af[r] = *(const bf16x8*)(&As[(wr + r * 16 + mr) * 32 + quad * 8]);
#pragma unroll
        for (int c = 0; c < 4; c++)
            bfv[c] = *(const bf16x8*)(&Bs[(wc + c * 16 + mr) * 32 + quad * 8]);
#pragma unroll
        for (int r = 0; r < RF; r++)
#pragma unroll
            for (int c = 0; c < 4; c++)
                acc[r][c] = MFMA(af[r], bfv[c], acc[r][c]);
        __syncthreads();
    }

    const long zC = (long)blockIdx.z * sC;
    float bias_c[4];
    if (EPI & 1) {
#pragma unroll
        for (int c = 0; c < 4; c++) bias_c[c] = bias[bN + wc + c * 16 + mr];
    }
#pragma unroll
    for (int r = 0; r < RF; r++) {
#pragma unroll
        for (int c = 0; c < 4; c++) {
            const long col = bN + wc + c * 16 + mr;
#pragma unroll
            for (int i = 0; i < 4; i++) {
                const long row = bM + wr + r * 16 + quad * 4 + i;
                float v = acc[r][c][i] * alpha;
                if (EPI & 1) v += bias_c[c];
                if (EPI & 2) v = fmaxf(v, 0.f);
                if (EPI & 4) ((bf16*)Cv)[zC + row * (long)N + col] = (bf16)v;
                else         ((float*)Cv)[zC + row * (long)N + col] = v;
            }
        }
    }
}

// ---------------- 256x256 ring-4 pipelined MFMA GEMM ----------------
// v2: de-lockstepped. Only the tile-boundary vmcnt(8)+barrier remains (1 barrier/
// K-tile, was 4). Correctness: ring distance 3 (stage targets slot (t+3)&3, reads
// touch slot t&3); within-iteration wave skew bounded by the boundary barrier;
// per-wave lgkmcnt(0) guards each wave's own ds_reads. Mid-tile barriers only
// enforced lockstep — cross-wave drift is the latency-hiding mechanism that works
// at 2 waves/SIMD (m97/flash evidence).
template<int EPI>
__launch_bounds__(512, 2)
__global__ void gemm256(const bf16* __restrict__ A, const bf16* __restrict__ Bt,
                        void* __restrict__ Cv, const float* __restrict__ bias,
                        int M, int N, int K, int lda, int ldb,
                        long sA, long sB, long sC, float alpha) {
    __shared__ __align__(16) bf16 LA[4][256 * 32];   // 4 x 16 KB
    __shared__ __align__(16) bf16 LB[4][256 * 32];   // 4 x 16 KB
    const int tid = threadIdx.x, wave = tid >> 6, lane = tid & 63;
    const int quad = lane >> 4, mr = lane & 15;
    const int wr = wave >> 2, wc = wave & 3;
    const int bM = blockIdx.x * 256, bN = blockIdx.y * 256;
    (void)M;
    A  += (long)blockIdx.z * sA;
    Bt += (long)blockIdx.z * sB;

    const int srow = tid >> 2;
    const int sg   = (((tid & 3) ^ ((tid >> 3) & 3))) * 8;
    const bf16* Ag = A  + (long)(bM + srow) * lda + sg;
    const bf16* Bg = Bt + (long)(bN + srow) * ldb + sg;

    auto stageA = [&](int slot, int kt) {
        const bf16* s = Ag + kt * 32;
        async16(s,                   &LA[slot][wave * 512]);
        async16(s + (long)128 * lda, &LA[slot][4096 + wave * 512]);
    };
    auto stageB = [&](int slot, int kt) {
        const bf16* s = Bg + kt * 32;
        async16(s,                   &LB[slot][wave * 512]);
        async16(s + (long)128 * ldb, &LB[slot][4096 + wave * 512]);
    };

    f32x4 acc[8][4];
#pragma unroll
    for (int f = 0; f < 8; f++)
#pragma unroll
        for (int n = 0; n < 4; n++) { f32x4 z = {0.f, 0.f, 0.f, 0.f}; acc[f][n] = z; }

    const int gsw = (quad ^ ((mr >> 1) & 3)) * 8;

    stageA(0, 0); stageB(0, 0);
    stageA(1, 1); stageB(1, 1);
    stageA(2, 2); stageB(2, 2);
    asm volatile("s_waitcnt vmcnt(8)" ::: "memory");
    __builtin_amdgcn_s_barrier();

    const int NT = K >> 5;
    for (int t = 0; t < NT; ++t) {
        const int slot = t & 3;
        const bf16* As = &LA[slot][0];
        const bf16* Bs = &LB[slot][0];

        bf16x8 a0[4], bb[4];
#pragma unroll
        for (int f = 0; f < 4; f++)
            a0[f] = *(const bf16x8*)(As + (wr * 128 + f * 16 + mr) * 32 + gsw);
#pragma unroll
        for (int n = 0; n < 4; n++)
            bb[n] = *(const bf16x8*)(Bs + (wc * 64 + n * 16 + mr) * 32 + gsw);
        if (t + 3 < NT) stageA((t + 3) & 3, t + 3);
        asm volatile("s_waitcnt lgkmcnt(0)" ::: "memory");
        __builtin_amdgcn_sched_barrier(0);
        __builtin_amdgcn_s_setprio(1);
#pragma unroll
        for (int f = 0; f < 4; f++)
#pragma unroll
            for (int n = 0; n < 4; n++)
                acc[f][n] = MFMA(a0[f], bb[n], acc[f][n]);
        __builtin_amdgcn_s_setprio(0);

        bf16x8 a1[4];
#pragma unroll
        for (int f = 0; f < 4; f++)
            a1[f] = *(const bf16x8*)(As + (wr * 128 + 64 + f * 16 + mr) * 32 + gsw);
        if (t + 3 < NT) stageB((t + 3) & 3, t + 3);
        asm volatile("s_waitcnt lgkmcnt(0)" ::: "memory");
        __builtin_amdgcn_sched_barrier(0);
        __builtin_amdgcn_s_setprio(1);
#pragma unroll
        for (int f = 0; f < 4; f++)
#pragma unroll
            for (int n = 0; n < 4; n++)
                acc[4 + f][n] = MFMA(a1[f], bb[n], acc[4 + f][n]);
        __builtin_amdgcn_s_setprio(0);
        // tile boundary: ONLY sync point. Ensures tile t+1's loads (issued iter
        // t-2) have landed for ALL waves, and bounds wave skew to one iteration.
        if (t < NT - 3)       asm volatile("s_waitcnt vmcnt(8)" ::: "memory");
        else if (t == NT - 3) asm volatile("s_waitcnt vmcnt(4)" ::: "memory");
        else if (t == NT - 2) asm volatile("s_waitcnt vmcnt(0)" ::: "memory");
        __builtin_amdgcn_s_barrier();
    }

    const long zC = (long)blockIdx.z * sC;
    float bias_c[4];
    if (EPI & 1) {
#pragma unroll
        for (int n = 0; n < 4; n++) bias_c[n] = bias[bN + wc * 64 + n * 16 + mr];
    }
#pragma unroll
    for (int f = 0; f < 8; f++) {
#pragma unroll
        for (int n = 0; n < 4; n++) {
            const long col = bN + wc * 64 + n * 16 + mr;
#pragma unroll
            for (int i = 0; i < 4; i++) {
                const long row = bM + wr * 128 + f * 16 + quad * 4 + i;
                float v = acc[f][n][i] * alpha;
                if (EPI & 1) v += bias_c[n];
                if (EPI & 2) v = fmaxf(v, 0.f);
                if (EPI & 4) ((bf16*)Cv)[zC + row * (long)N + col] = (bf16)v;
                else         ((float*)Cv)[zC + row * (long)N + col] = v;
            }
        }
    }
}

// ---------------- fused flash attention with relevance bias, K-split ----------------
// Proven body (4 waves, 128-row Q-tile, single-buffered 2-barrier loop, 51 KB LDS)
// + T1 bijective XCD chunking + T5 setprio. v2: exp via exp2f with folded constant
// (one v_mul fewer per softmax entry; llvm.exp2 maps 1:1 to v_exp_f32).
template<int SPLIT>
__launch_bounds__(256, 1)
__global__ void flash_attn(const bf16* __restrict__ qb, const bf16* __restrict__ kT,
                           const bf16* __restrict__ vT, const float* __restrict__ rq,
                           const float* __restrict__ rk, bf16* __restrict__ ctx,
                           float* __restrict__ opart, float* __restrict__ osum) {
    __shared__ __align__(16) bf16  Ksh[KT_ * HD_];   // [key][d], granule-swizzled
    __shared__ __align__(16) bf16  Vsh[HD_ * KT_];   // [d][key], granule-swizzled
    __shared__ __align__(16) float rks[4 * KT_];     // [r][key] fp32
    __shared__ __align__(16) bf16  Ps[4][32 * PSTR]; // per-wave P, 16B-aligned rows

    const int tid = threadIdx.x, wave = tid >> 6, lane = tid & 63;
    const int quad = lane >> 4, mr = lane & 15;
    const int nwg = 256 * SPLIT;
    const int lid = blockIdx.x + (blockIdx.y << 4) + (blockIdx.z << 8);
    const int wid = (lid & 7) * (nwg >> 3) + (lid >> 3);
    const int ksp = wid >> 8;
    const int pair = (wid >> 4) & 15, b = pair >> 3;
    const int bQ = (wid & 15) * 128;
    const long PB = (long)pair * L_ * HD_;
    const bf16* Qg = qb + PB;
    const bf16* Kg = kT + PB;
    const bf16* Vg = vT + PB;
    const float* rkb = rk + (long)b * L_ * 4;

    // Q fragments in registers (A-layout): rows bQ + wave*32 + f*16 + mr
    bf16x8 Qf[2][4], Qe[2];
#pragma unroll
    for (int f = 0; f < 2; f++) {
#pragma unroll
        for (int t = 0; t < 4; t++)
            Qf[f][t] = *(const bf16x8*)(Qg + (long)(bQ + wave * 32 + f * 16 + mr) * HD_ + t * 32 + quad * 8);
        bf16x8 z = {};
        if (quad == 0) {
            float4 v = *(const float4*)(rq + ((long)b * L_ + bQ + wave * 32 + f * 16 + mr) * 4);
            z[0] = (bf16)(v.x * RSCALE_); z[1] = (bf16)(v.y * RSCALE_);
            z[2] = (bf16)(v.z * RSCALE_); z[3] = (bf16)(v.w * RSCALE_);
        }
        Qe[f] = z;
    }

    bf16x8 ones;
#pragma unroll
    for (int j = 0; j < 8; j++) ones[j] = (bf16)1.0f;

    f32x4 O[2][8], Os[2];
#pragma unroll
    for (int f = 0; f < 2; f++) {
#pragma unroll
        for (int c = 0; c < 8; c++) { f32x4 z = {0.f, 0.f, 0.f, 0.f}; O[f][c] = z; }
        f32x4 z = {0.f, 0.f, 0.f, 0.f}; Os[f] = z;
    }

    const int tile0 = ksp * ((L_ / KT_) / SPLIT);
    const int tile1 = tile0 + (L_ / KT_) / SPLIT;
    for (int kt = tile0; kt < tile1; kt++) {
        const int kt0 = kt * KT_;
        // ---- stage K/V/rk (single buffer) ----
#pragma unroll
        for (int it = 0; it < 4; it++) {
            int G = it * 256 + tid;
            int r1 = G >> 4, g1 = (G & 15) ^ (r1 & 15);
            async16(Kg + (long)(kt0 + r1) * HD_ + g1 * 8, &Ksh[(it * 256 + wave * 64) * 8]);
            int r2 = G >> 3, g2 = (G & 7) ^ (r2 & 7);
            async16(Vg + (long)r2 * L_ + kt0 + g2 * 8, &Vsh[(it * 256 + wave * 64) * 8]);
        }
        if (tid < 64) {
            int r3 = tid >> 4, g3 = tid & 15;
            async16((const bf16*)(rkb + (long)r3 * L_ + kt0 + g3 * 4), (bf16*)&rks[0]);
        }
        __syncthreads();   // drains vmcnt -> LDS valid for all waves

        bf16* PsW = Ps[wave];

        // ---- S = Q K^T (+ ext bias chunk), 4 col-blocks of 16 keys ----
        f32x4 sc[4][2];
        __builtin_amdgcn_s_setprio(1);
#pragma unroll
        for (int c = 0; c < 4; c++) {
            f32x4 s0 = {0.f, 0.f, 0.f, 0.f}, s1 = s0;
#pragma unroll
            for (int t = 0; t < 4; t++) {
                bf16x8 kf = *(const bf16x8*)(Ksh + (c * 16 + mr) * HD_ + (((t * 4 + quad) ^ mr) * 8));
                s0 = MFMA(Qf[0][t], kf, s0);
                s1 = MFMA(Qf[1][t], kf, s1);
            }
            bf16x8 ke = {};
            if (quad == 0) {
                ke[0] = (bf16)rks[0 * KT_ + c * 16 + mr];
                ke[1] = (bf16)rks[1 * KT_ + c * 16 + mr];
                ke[2] = (bf16)rks[2 * KT_ + c * 16 + mr];
                ke[3] = (bf16)rks[3 * KT_ + c * 16 + mr];
            }
            s0 = MFMA(Qe[0], ke, s0);
            s1 = MFMA(Qe[1], ke, s1);
            sc[c][0] = s0; sc[c][1] = s1;
        }
        __builtin_amdgcn_s_setprio(0);

        // ---- P = exp2(S*EXP2S) straight to LDS (no max, no shuffles) ----
#pragma unroll
        for (int f = 0; f < 2; f++) {
#pragma unroll
            for (int i = 0; i < 4; i++) {
                const int prow = (f * 16 + quad * 4 + i) * PSTR;
                PsW[prow + 0 * 16 + mr] = (bf16)exp2f(sc[0][f][i] * EXP2S_);
                PsW[prow + 1 * 16 + mr] = (bf16)exp2f(sc[1][f][i] * EXP2S_);
                PsW[prow + 2 * 16 + mr] = (bf16)exp2f(sc[2][f][i] * EXP2S_);
                PsW[prow + 3 * 16 + mr] = (bf16)exp2f(sc[3][f][i] * EXP2S_);
            }
        }

        // ---- O += P @ V ; Os += P @ ones (row sums) ----
        __builtin_amdgcn_s_setprio(1);
#pragma unroll
        for (int t = 0; t < 2; t++) {
            bf16x8 pf0 = *(const bf16x8*)(PsW + (0 * 16 + mr) * PSTR + t * 32 + quad * 8);
            bf16x8 pf1 = *(const bf16x8*)(PsW + (1 * 16 + mr) * PSTR + t * 32 + quad * 8);
            Os[0] = MFMA(pf0, ones, Os[0]);
            Os[1] = MFMA(pf1, ones, Os[1]);
#pragma unroll
            for (int c2 = 0; c2 < 8; c2++) {
                bf16x8 vf = *(const bf16x8*)(Vsh + (c2 * 16 + mr) * KT_ + (((t * 4 + quad) ^ (mr & 7)) * 8));
                O[0][c2] = MFMA(pf0, vf, O[0][c2]);
                O[1][c2] = MFMA(pf1, vf, O[1][c2]);
            }
        }
        __builtin_amdgcn_s_setprio(0);
        __syncthreads();   // all waves done reading K/V before restage
    }

    // ---- epilogue ----
    if (SPLIT == 1) {
        bf16* Cg = ctx + PB;
#pragma unroll
        for (int f = 0; f < 2; f++)
#pragma unroll
            for (int i = 0; i < 4; i++) {
                const float inv = 1.f / Os[f][i];
                const long row = bQ + wave * 32 + f * 16 + quad * 4 + i;
#pragma unroll
                for (int c2 = 0; c2 < 8; c2++)
                    Cg[row * HD_ + c2 * 16 + mr] = (bf16)(O[f][c2][i] * inv);
            }
    } else {
        float* Og = opart + (long)ksp * ((long)PAIRS_ * L_ * HD_) + PB;
        float* Sg = osum + (long)ksp * (PAIRS_ * L_) + pair * L_;
#pragma unroll
        for (int f = 0; f < 2; f++)
#pragma unroll
            for (int i = 0; i < 4; i++) {
                const long row = bQ + wave * 32 + f * 16 + quad * 4 + i;
#pragma unroll
                for (int c2 = 0; c2 < 8; c2++)
                    Og[row * HD_ + c2 * 16 + mr] = O[f][c2][i];
                if (mr == 0) Sg[row] = Os[f][i];
            }
    }
}

// --------- combine KS flash partials: ctx = (sum O_z) / (sum s_z) ----------
template<int KS>
__global__ void flash_reduce(const float* __restrict__ op, const float* __restrict__ os,
                             bf16* __restrict__ ctx) {
    const long PLHD = (long)PAIRS_ * L_ * HD_;
    long e = ((long)blockIdx.x * 256 + threadIdx.x) * 4;
    long row = e >> 7;                       // / HD_
    float4 a = *(const float4*)(op + e);
    float s = os[row];
#pragma unroll
    for (int z = 1; z < KS; z++) {
        float4 p = *(const float4*)(op + (long)z * PLHD + e);
        a.x += p.x; a.y += p.y; a.z += p.z; a.w += p.w;
        s += os[(long)z * PAIRS_ * L_ + row];
    }
    float inv = 1.f / s;
    bf16x4 o = {(bf16)(a.x * inv), (bf16)(a.y * inv),
                (bf16)(a.z * inv), (bf16)(a.w * inv)};
    *(bf16x4*)(ctx + e) = o;
}

// ---------------- LN1: layernorm(x1 + x2) * g + be ; fp32 + bf16 out ----------------
__global__ void layernorm_res(const float* __restrict__ x1, const float* __restrict__ x2,
                              const float* __restrict__ g, const float* __restrict__ be,
                              float* __restrict__ outf, bf16* __restrict__ outb) {
    const int row = blockIdx.x, tid = threadIdx.x;
    const long base = (long)row * D_ + tid * 4;
    float4 a = *(const float4*)(x1 + base);
    float4 b = *(const float4*)(x2 + base);
    float x[4] = {a.x + b.x, a.y + b.y, a.z + b.z, a.w + b.w};
    float s = x[0] + x[1] + x[2] + x[3];
    float s2 = x[0] * x[0] + x[1] * x[1] + x[2] * x[2] + x[3] * x[3];
#pragma unroll
    for (int off = 32; off; off >>= 1) { s += __shfl_xor(s, off, 64); s2 += __shfl_xor(s2, off, 64); }
    __shared__ float ps[4], ps2[4];
    int wave = tid >> 6, lane = tid & 63;
    if (lane == 0) { ps[wave] = s; ps2[wave] = s2; }
    __syncthreads();
    s  = ps[0] + ps[1] + ps[2] + ps[3];
    s2 = ps2[0] + ps2[1] + ps2[2] + ps2[3];
    float mean = s * (1.f / D_);
    float var  = s2 * (1.f / D_) - mean * mean;
    float rstd = rsqrtf(var + 1e-5f);
    float4 gg = *(const float4*)(g + tid * 4);
    float4 bb = *(const float4*)(be + tid * 4);
    float y0 = (x[0] - mean) * rstd * gg.x + bb.x;
    float y1 = (x[1] - mean) * rstd * gg.y + bb.y;
    float y2 = (x[2] - mean) * rstd * gg.z + bb.z;
    float y3 = (x[3] - mean) * rstd * gg.w + bb.w;
    float4 yo = {y0, y1, y2, y3};
    *(float4*)(outf + base) = yo;
    bf16x4 ob = {(bf16)y0, (bf16)y1, (bf16)y2, (bf16)y3};
    *(bf16x4*)(outb + base) = ob;
}

// ---------------- LN2: layernorm(sum_z parts[z] + b2 + h1) * g + be -> fp32 ----------
template<int SK>
__global__ void layernorm_res2(const float* __restrict__ parts, const float* __restrict__ b2,
                               const float* __restrict__ x2, const float* __restrict__ g,
                               const float* __restrict__ be, float* __restrict__ outf) {
    const int row = blockIdx.x, tid = threadIdx.x;
    const long base = (long)row * D_ + tid * 4;
    float4 a = *(const float4*)(parts + base);
#pragma unroll
    for (int z = 1; z < SK; z++) {
        float4 p = *(const float4*)(parts + (long)z * ROWS_ * D_ + base);
        a.x += p.x; a.y += p.y; a.z += p.z; a.w += p.w;
    }
    float4 bb2 = *(const float4*)(b2 + tid * 4);
    float4 b = *(const float4*)(x2 + base);
    float x[4] = {a.x + bb2.x + b.x, a.y + bb2.y + b.y, a.z + bb2.z + b.z, a.w + bb2.w + b.w};
    float s = x[0] + x[1] + x[2] + x[3];
    float s2 = x[0] * x[0] + x[1] * x[1] + x[2] * x[2] + x[3] * x[3];
#pragma unroll
    for (int off = 32; off; off >>= 1) { s += __shfl_xor(s, off, 64); s2 += __shfl_xor(s2, off, 64); }
    __shared__ float ps[4], ps2[4];
    int wave = tid >> 6, lane = tid & 63;
    if (lane == 0) { ps[wave] = s; ps2[wave] = s2; }
    __syncthreads();
    s  = ps[0] + ps[1] + ps[2] + ps[3];
    s2 = ps2[0] + ps2[1] + ps2[2] + ps2[3];
    float mean = s * (1.f / D_);
    float var  = s2 * (1.f / D_) - mean * mean;
    float rstd = rsqrtf(var + 1e-5f);
    float4 gg = *(const float4*)(g + tid * 4);
    float4 bb = *(const float4*)(be + tid * 4);
    float4 yo = {(x[0] - mean) * rstd * gg.x + bb.x, (x[1] - mean) * rstd * gg.y + bb.y,
                 (x[2] - mean) * rstd * gg.z + bb.z, (x[3] - mean) * rstd * gg.w + bb.w};
    *(float4*)(outf + base) = yo;
}

// ---------------- launch ----------------
extern "C" void kernel_launch(void* const* d_in, const int* in_sizes, int n_in,
                              void* d_out, int out_size, void* d_ws, size_t ws_size,
                              hipStream_t stream) {
    (void)in_sizes; (void)n_in; (void)out_size;
    const float* h   = (const float*)d_in[0];
    const float* rh  = (const float*)d_in[1];
    const float* Wq  = (const float*)d_in[2];
    const float* Wk  = (const float*)d_in[3];
    const float* Wv  = (const float*)d_in[4];
    const float* Wo  = (const float*)d_in[5];
    const float* Wrk = (const float*)d_in[6];
    const float* Wrq = (const float*)d_in[7];
    const float* W1  = (const float*)d_in[8];
    const float* b1  = (const float*)d_in[9];
    const float* W2  = (const float*)d_in[10];
    const float* b2  = (const float*)d_in[11];
    const float* g1  = (const float*)d_in[12];
    const float* be1 = (const float*)d_in[13];
    const float* g2  = (const float*)d_in[14];
    const float* be2 = (const float*)d_in[15];

    char* w = (char*)d_ws;
    size_t used = 0;
    auto alloc = [&](size_t bytes) { char* p = w + used; used += (bytes + 255) & ~(size_t)255; return p; };
    bf16*  hb   = (bf16*)alloc((size_t)ROWS_ * D_ * 2);       // 8 MB; later ctx, then h1b
    bf16*  Wqt  = (bf16*)alloc((size_t)D_ * D_ * 2);
    bf16*  Wkt  = (bf16*)alloc((size_t)D_ * D_ * 2);
    bf16*  Wvt  = (bf16*)alloc((size_t)D_ * D_ * 2);
    bf16*  Wot  = (bf16*)alloc((size_t)D_ * D_ * 2);
    bf16*  W1t  = (bf16*)alloc((size_t)D_ * FFN_ * 2);
    bf16*  W2t  = (bf16*)alloc((size_t)FFN_ * D_ * 2);
    bf16*  qb   = (bf16*)alloc((size_t)ROWS_ * D_ * 2);       // qb/kb/vb contiguous (z-batch out)
    bf16*  kb   = (bf16*)alloc((size_t)ROWS_ * D_ * 2);
    bf16*  vb   = (bf16*)alloc((size_t)ROWS_ * D_ * 2);
    bf16*  kT   = (bf16*)alloc((size_t)ROWS_ * D_ * 2);       // kT[m][d] = chunk[d*L+m]
    bf16*  vT   = (bf16*)alloc((size_t)ROWS_ * D_ * 2);       // vT[d][key]
    float* rq   = (float*)alloc((size_t)ROWS_ * 4 * 4);
    float* rk   = (float*)alloc((size_t)ROWS_ * 4 * 4);
    float* h1   = (float*)alloc((size_t)ROWS_ * D_ * 4);      // 16 MB, live to the end

    const size_t psz    = (size_t)ROWS_ * D_ * 4;             // 16 MB
    const size_t PLHD   = (size_t)PAIRS_ * L_ * HD_;          // elements
    const size_t needKS = 2 * PLHD * 4 + 2 * (size_t)PAIRS_ * L_ * 4;  // ~32.25 MB
    const size_t avail  = (ws_size > used) ? ws_size - used : 0;
    const int SK = (avail >= 4 * psz) ? 4 : (avail >= 2 * psz) ? 2 : 1;
    size_t region = (size_t)SK * psz;
    const int KS = (avail >= (needKS > region ? needKS : region)) ? 2 : 1;
    if (KS == 2 && needKS > region) region = needKS;
    float* P = (float*)alloc(region);
    float* hsa   = P;
    float* Opart = P;
    float* Osum  = P + 2 * PLHD;
    bf16* ctx = hb;
    bf16* mid = qb;    // 32 MB over qb..kT, live after flash
    bf16* h1b = hb;    // over hb, live after Wo

    const dim3 blk(256);
    const dim3 blk512(512);

    // 1. ALL preprocessing in one dispatch: cvt + 6 weight transposes + rqk
    prep_kernel<<<16400, blk, 0, stream>>>(h, hb, Wq, Wk, Wv, Wo, Wqt, Wkt, Wvt, Wot,
                                           W1, W1t, W2, W2t, rh, Wrq, Wrk, rq, rk);
    // 2. QKV projections, z=3 batched (192 blocks, 256^2 ring-4)
    gemm256<4><<<dim3(16, 4, 3), blk512, 0, stream>>>(hb, Wqt, qb, nullptr,
        ROWS_, D_, D_, D_, D_, 0, (long)D_ * D_, (long)ROWS_ * D_, 1.f);
    // 3. per-(b,n) K and V transposes in one dispatch
    transposeKV<<<8192, blk, 0, stream>>>(kb, kT, vb, vT);
    // 4. fused flash attention -> ctx (K-split 2 when workspace allows)
    if (KS == 2) {
        flash_attn<2><<<dim3(16, 16, 2), blk, 0, stream>>>(qb, kT, vT, rq, rk, ctx, Opart, Osum);
        flash_reduce<2><<<PAIRS_ * L_ * HD_ / 1024, blk, 0, stream>>>(Opart, Osum, ctx);
    } else {
        flash_attn<1><<<dim3(16, 16, 1), blk, 0, stream>>>(qb, kT, vT, rq, rk, ctx, Opart, Osum);
    }
    // 5. h_sa = ctx @ Wo (fp32)
    gemm128<64, 0><<<dim3(64, 8, 1), blk, 0, stream>>>(ctx, Wot, hsa, nullptr,
        ROWS_, D_, D_, D_, D_, 0, 0, 0, 1.f);
    // 6. h1 = LN(h_sa + h)
    layernorm_res<<<ROWS_, blk, 0, stream>>>(hsa, h, g1, be1, h1, h1b);
    // 7. mid = relu(h1 @ W1 + b1)  (256 blocks, 256^2 ring-4)
    gemm256<7><<<dim3(16, 16, 1), blk512, 0, stream>>>(h1b, W1t, mid, b1,
        ROWS_, FFN_, D_, D_, D_, 0, 0, 0, 1.f);
    // 8-9. hf partials ; out = LN(h1 + sum + b2)
    {
        const int KC = FFN_ / SK;
        if (SK == 4) {
            gemm256<0><<<dim3(16, 4, 4), blk512, 0, stream>>>(mid, W2t, P, nullptr,
                ROWS_, D_, KC, FFN_, FFN_, KC, KC, (long)ROWS_ * D_, 1.f);
            layernorm_res2<4><<<ROWS_, blk, 0, stream>>>(P, b2, h1, g2, be2, (float*)d_out);
        } else if (SK == 2) {
            gemm256<0><<<dim3(16, 4, 2), blk512, 0, stream>>>(mid, W2t, P, nullptr,
                ROWS_, D_, KC, FFN_, FFN_, KC, KC, (long)ROWS_ * D_, 1.f);
            layernorm_res2<2><<<ROWS_, blk, 0, stream>>>(P, b2, h1, g2, be2, (float*)d_out);
        } else {
            gemm128<128, 0><<<dim3(32, 8, 1), blk, 0, stream>>>(mid, W2t, P, nullptr,
                ROWS_, D_, FFN_, FFN_, FFN_, 0, 0, 0, 1.f);
            layernorm_res2<1><<<ROWS_, blk, 0, stream>>>(P, b2, h1, g2, be2, (float*)d_out);
        }
    }
}

// Round 11
// 359.595 us; speedup vs baseline: 1.3250x; 1.0109x over previous
//
#include <hip/hip_runtime.h>

typedef __bf16 bf16;
typedef __bf16 bf16x8 __attribute__((ext_vector_type(8)));
typedef __bf16 bf16x4 __attribute__((ext_vector_type(4)));
typedef float  f32x4  __attribute__((ext_vector_type(4)));

#define D_     1024
#define FFN_   4096
#define NH_    8
#define HD_    128
#define L_     2048
#define B_     2
#define ROWS_  4096           // B_*L_
#define PAIRS_ 16             // B_*NH_
#define KT_    64             // flash K-tile (keys)
#define PSTR   72             // Ps row stride (bf16): 144 B = 16B-aligned rows
#define ALPHA_  0.08838834764831845f   // 1/sqrt(128)
#define RSCALE_ 5.656854249492381f     // 0.5/ALPHA_

// async 16B global -> LDS (wave-uniform LDS base + lane*16 implicit)
__device__ __forceinline__ void async16(const bf16* g, bf16* l) {
    __builtin_amdgcn_global_load_lds(
        (const __attribute__((address_space(1))) unsigned int*)g,
        (__attribute__((address_space(3))) unsigned int*)l, 16, 0, 0);
}
__device__ __forceinline__ f32x4 MFMA(bf16x8 a, bf16x8 b, f32x4 c) {
    return __builtin_amdgcn_mfma_f32_16x16x32_bf16(a, b, c, 0, 0, 0);
}

// ---------------- mega-prep: ONE dispatch for all preprocessing ----------------
__global__ void prep_kernel(const float* __restrict__ h, bf16* __restrict__ hb,
                            const float* __restrict__ Wq, const float* __restrict__ Wk,
                            const float* __restrict__ Wv, const float* __restrict__ Wo,
                            bf16* __restrict__ Wqt, bf16* __restrict__ Wkt,
                            bf16* __restrict__ Wvt, bf16* __restrict__ Wot,
                            const float* __restrict__ W1, bf16* __restrict__ W1t,
                            const float* __restrict__ W2, bf16* __restrict__ W2t,
                            const float* __restrict__ rh, const float* __restrict__ Wrq,
                            const float* __restrict__ Wrk, float* __restrict__ rq,
                            float* __restrict__ rk) {
    __shared__ bf16 t[32][33];
    int bid = blockIdx.x;
    if (bid < 4096) {                      // ---- cvt h -> hb ----
        long i = ((long)bid * 256 + threadIdx.x) * 4;
        float4 v = *(const float4*)(h + i);
        bf16x4 o = {(bf16)v.x, (bf16)v.y, (bf16)v.z, (bf16)v.w};
        *(bf16x4*)(hb + i) = o;
        return;
    }
    bid -= 4096;
    if (bid >= 12288) {                    // ---- rqk (16 blocks) ----
        int tt = (bid - 12288) * 256 + threadIdx.x;
        float4 r = *(const float4*)(rh + (long)tt * 4);
        float q[4], k[4];
#pragma unroll
        for (int c = 0; c < 4; c++) {
            q[c] = r.x * Wrq[c] + r.y * Wrq[4 + c] + r.z * Wrq[8 + c] + r.w * Wrq[12 + c];
            k[c] = r.x * Wrk[c] + r.y * Wrk[4 + c] + r.z * Wrk[8 + c] + r.w * Wrk[12 + c];
        }
        float4 qo = {q[0], q[1], q[2], q[3]};
        float4 ko = {k[0], k[1], k[2], k[3]};
        *(float4*)(rq + (long)tt * 4) = qo;
        *(float4*)(rk + (long)tt * 4) = ko;
        return;
    }
    const float* in; bf16* out; int r, c, x0, y0;
    if (bid < 4096) {                      // Wq/Wk/Wv/Wo: 1024 blocks each
        int m = bid >> 10, xy = bid & 1023;
        switch (m) { case 0: in = Wq; out = Wqt; break;
                     case 1: in = Wk; out = Wkt; break;
                     case 2: in = Wv; out = Wvt; break;
                     default: in = Wo; out = Wot; break; }
        r = D_; c = D_;
        x0 = (xy & 31) * 32; y0 = (xy >> 5) * 32;
    } else if (bid < 8192) {               // W1 [D][FFN] -> [FFN][D]
        int xy = bid - 4096;
        in = W1; out = W1t; r = D_; c = FFN_;
        x0 = (xy & 127) * 32; y0 = (xy >> 7) * 32;
    } else {                               // W2 [FFN][D] -> [D][FFN]
        int xy = bid - 8192;
        in = W2; out = W2t; r = FFN_; c = D_;
        x0 = (xy & 31) * 32; y0 = (xy >> 5) * 32;
    }
    int tx = threadIdx.x & 31, ty = threadIdx.x >> 5;  // 32 x 8
#pragma unroll
    for (int i = 0; i < 4; i++)
        t[ty + i * 8][tx] = (bf16)in[(long)(y0 + ty + i * 8) * c + x0 + tx];
    __syncthreads();
#pragma unroll
    for (int i = 0; i < 4; i++)
        out[(long)(x0 + ty + i * 8) * r + y0 + tx] = t[tx][ty + i * 8];
}

// ---------------- fused per-pair K and V transposes (one dispatch) ----------------
__global__ void transposeKV(const bf16* __restrict__ kb, bf16* __restrict__ kTo,
                            const bf16* __restrict__ vb, bf16* __restrict__ vTo) {
    __shared__ bf16 t[32][33];
    int bid = blockIdx.x;
    const bf16* in; bf16* out; int r, c, x0, y0; long zoff;
    if (bid < 4096) {
        int z = bid >> 8, xy = bid & 255;   // 256 tiles/pair: x 64, y 4
        in = kb; out = kTo; r = HD_; c = L_;
        x0 = (xy & 63) * 32; y0 = (xy >> 6) * 32;
        zoff = (long)z * (L_ * HD_);
    } else {
        int b2 = bid - 4096;
        int z = b2 >> 8, xy = b2 & 255;     // 256 tiles/pair: x 4, y 64
        in = vb; out = vTo; r = L_; c = HD_;
        x0 = (xy & 3) * 32; y0 = (xy >> 2) * 32;
        zoff = (long)z * (L_ * HD_);
    }
    int tx = threadIdx.x & 31, ty = threadIdx.x >> 5;
#pragma unroll
    for (int i = 0; i < 4; i++)
        t[ty + i * 8][tx] = in[zoff + (long)(y0 + ty + i * 8) * c + x0 + tx];
    __syncthreads();
#pragma unroll
    for (int i = 0; i < 4; i++)
        out[zoff + (long)(x0 + ty + i * 8) * r + y0 + tx] = t[tx][ty + i * 8];
}

// ---------------- m97-style MFMA GEMM (Wo + fallback) ----------------
template<int BM, int EPI>
__launch_bounds__(256)
__global__ void gemm128(const bf16* __restrict__ A, const bf16* __restrict__ Bt,
                        void* __restrict__ Cv, const float* __restrict__ bias,
                        int M, int N, int K, int lda, int ldb,
                        long sA, long sB, long sC, float alpha) {
    constexpr int RF = (BM == 128) ? 4 : 2;
    __shared__ __align__(16) bf16 As[BM * 32];
    __shared__ __align__(16) bf16 Bs[128 * 32];
    const int tid  = threadIdx.x;
    const int wave = tid >> 6, lane = tid & 63;
    const int quad = lane >> 4, mr = lane & 15;
    const int bM = blockIdx.x * BM, bN = blockIdx.y * 128;
    A  += (long)blockIdx.z * sA;
    Bt += (long)blockIdx.z * sB;
    const int wr = (wave >> 1) * (BM / 2), wc = (wave & 1) * 64;

    f32x4 acc[RF][4];
#pragma unroll
    for (int r = 0; r < RF; r++)
#pragma unroll
        for (int c = 0; c < 4; c++) { f32x4 z = {0.f, 0.f, 0.f, 0.f}; acc[r][c] = z; }

    const int scol = (lane & 3) * 8;
    const bf16* Ag0; const bf16* Ag1 = nullptr;
    if (BM == 128) {
        const int srow = wave * 32 + (lane >> 2);
        Ag0 = A + (long)(bM + srow) * lda + scol;
        Ag1 = Ag0 + (long)16 * lda;
    } else {
        const int srow = wave * 16 + (lane >> 2);
        Ag0 = A + (long)(bM + srow) * lda + scol;
    }
    const int srowB = wave * 32 + (lane >> 2);
    const bf16* Bg0 = Bt + (long)(bN + srowB) * ldb + scol;
    const bf16* Bg1 = Bg0 + (long)16 * ldb;
    bf16* AsW = As + wave * (BM == 128 ? 1024 : 512);
    bf16* BsW = Bs + wave * 1024;

    for (int k0 = 0; k0 < K; k0 += 32) {
        if (BM == 128) { async16(Ag0, AsW); async16(Ag1, AsW + 512); Ag0 += 32; Ag1 += 32; }
        else           { async16(Ag0, AsW); Ag0 += 32; }
        async16(Bg0, BsW); async16(Bg1, BsW + 512);
        Bg0 += 32; Bg1 += 32;
        __syncthreads();
        bf16x8 af[RF], bfv[4];
#pragma unroll
        for (int r = 0; r < RF; r++)
            af[r] = *(const bf16x8*)(&As[(wr + r * 16 + mr) * 32 + quad * 8]);
#pragma unroll
        for (int c = 0; c < 4; c++)
            bfv[c] = *(const bf16x8*)(&Bs[(wc + c * 16 + mr) * 32 + quad * 8]);
#pragma unroll
        for (int r = 0; r < RF; r++)
#pragma unroll
            for (int c = 0; c < 4; c++)
                acc[r][c] = MFMA(af[r], bfv[c], acc[r][c]);
        __syncthreads();
    }

    const long zC = (long)blockIdx.z * sC;
    float bias_c[4];
    if (EPI & 1) {
#pragma unroll
        for (int c = 0; c < 4; c++) bias_c[c] = bias[bN + wc + c * 16 + mr];
    }
#pragma unroll
    for (int r = 0; r < RF; r++) {
#pragma unroll
        for (int c = 0; c < 4; c++) {
            const long col = bN + wc + c * 16 + mr;
#pragma unroll
            for (int i = 0; i < 4; i++) {
                const long row = bM + wr + r * 16 + quad * 4 + i;
                float v = acc[r][c][i] * alpha;
                if (EPI & 1) v += bias_c[c];
                if (EPI & 2) v = fmaxf(v, 0.f);
                if (EPI & 4) ((bf16*)Cv)[zC + row * (long)N + col] = (bf16)v;
                else         ((float*)Cv)[zC + row * (long)N + col] = v;
            }
        }
    }
}

// ---------------- 256x256 ring-4 pipelined MFMA GEMM (de-lockstepped) ----------------
// 1 barrier/K-tile (was 4) — verified win in round 10 (~9 us across 3 dispatches).
// Correctness: ring distance 3; within-iteration wave skew bounded by the boundary
// barrier; per-wave lgkmcnt(0) guards each wave's own ds_reads.
template<int EPI>
__launch_bounds__(512, 2)
__global__ void gemm256(const bf16* __restrict__ A, const bf16* __restrict__ Bt,
                        void* __restrict__ Cv, const float* __restrict__ bias,
                        int M, int N, int K, int lda, int ldb,
                        long sA, long sB, long sC, float alpha) {
    __shared__ __align__(16) bf16 LA[4][256 * 32];   // 4 x 16 KB
    __shared__ __align__(16) bf16 LB[4][256 * 32];   // 4 x 16 KB
    const int tid = threadIdx.x, wave = tid >> 6, lane = tid & 63;
    const int quad = lane >> 4, mr = lane & 15;
    const int wr = wave >> 2, wc = wave & 3;
    const int bM = blockIdx.x * 256, bN = blockIdx.y * 256;
    (void)M;
    A  += (long)blockIdx.z * sA;
    Bt += (long)blockIdx.z * sB;

    const int srow = tid >> 2;
    const int sg   = (((tid & 3) ^ ((tid >> 3) & 3))) * 8;
    const bf16* Ag = A  + (long)(bM + srow) * lda + sg;
    const bf16* Bg = Bt + (long)(bN + srow) * ldb + sg;

    auto stageA = [&](int slot, int kt) {
        const bf16* s = Ag + kt * 32;
        async16(s,                   &LA[slot][wave * 512]);
        async16(s + (long)128 * lda, &LA[slot][4096 + wave * 512]);
    };
    auto stageB = [&](int slot, int kt) {
        const bf16* s = Bg + kt * 32;
        async16(s,                   &LB[slot][wave * 512]);
        async16(s + (long)128 * ldb, &LB[slot][4096 + wave * 512]);
    };

    f32x4 acc[8][4];
#pragma unroll
    for (int f = 0; f < 8; f++)
#pragma unroll
        for (int n = 0; n < 4; n++) { f32x4 z = {0.f, 0.f, 0.f, 0.f}; acc[f][n] = z; }

    const int gsw = (quad ^ ((mr >> 1) & 3)) * 8;

    stageA(0, 0); stageB(0, 0);
    stageA(1, 1); stageB(1, 1);
    stageA(2, 2); stageB(2, 2);
    asm volatile("s_waitcnt vmcnt(8)" ::: "memory");
    __builtin_amdgcn_s_barrier();

    const int NT = K >> 5;
    for (int t = 0; t < NT; ++t) {
        const int slot = t & 3;
        const bf16* As = &LA[slot][0];
        const bf16* Bs = &LB[slot][0];

        bf16x8 a0[4], bb[4];
#pragma unroll
        for (int f = 0; f < 4; f++)
            a0[f] = *(const bf16x8*)(As + (wr * 128 + f * 16 + mr) * 32 + gsw);
#pragma unroll
        for (int n = 0; n < 4; n++)
            bb[n] = *(const bf16x8*)(Bs + (wc * 64 + n * 16 + mr) * 32 + gsw);
        if (t + 3 < NT) stageA((t + 3) & 3, t + 3);
        asm volatile("s_waitcnt lgkmcnt(0)" ::: "memory");
        __builtin_amdgcn_sched_barrier(0);
        __builtin_amdgcn_s_setprio(1);
#pragma unroll
        for (int f = 0; f < 4; f++)
#pragma unroll
            for (int n = 0; n < 4; n++)
                acc[f][n] = MFMA(a0[f], bb[n], acc[f][n]);
        __builtin_amdgcn_s_setprio(0);

        bf16x8 a1[4];
#pragma unroll
        for (int f = 0; f < 4; f++)
            a1[f] = *(const bf16x8*)(As + (wr * 128 + 64 + f * 16 + mr) * 32 + gsw);
        if (t + 3 < NT) stageB((t + 3) & 3, t + 3);
        asm volatile("s_waitcnt lgkmcnt(0)" ::: "memory");
        __builtin_amdgcn_sched_barrier(0);
        __builtin_amdgcn_s_setprio(1);
#pragma unroll
        for (int f = 0; f < 4; f++)
#pragma unroll
            for (int n = 0; n < 4; n++)
                acc[4 + f][n] = MFMA(a1[f], bb[n], acc[4 + f][n]);
        __builtin_amdgcn_s_setprio(0);
        // tile boundary: ONLY sync point.
        if (t < NT - 3)       asm volatile("s_waitcnt vmcnt(8)" ::: "memory");
        else if (t == NT - 3) asm volatile("s_waitcnt vmcnt(4)" ::: "memory");
        else if (t == NT - 2) asm volatile("s_waitcnt vmcnt(0)" ::: "memory");
        __builtin_amdgcn_s_barrier();
    }

    const long zC = (long)blockIdx.z * sC;
    float bias_c[4];
    if (EPI & 1) {
#pragma unroll
        for (int n = 0; n < 4; n++) bias_c[n] = bias[bN + wc * 64 + n * 16 + mr];
    }
#pragma unroll
    for (int f = 0; f < 8; f++) {
#pragma unroll
        for (int n = 0; n < 4; n++) {
            const long col = bN + wc * 64 + n * 16 + mr;
#pragma unroll
            for (int i = 0; i < 4; i++) {
                const long row = bM + wr * 128 + f * 16 + quad * 4 + i;
                float v = acc[f][n][i] * alpha;
                if (EPI & 1) v += bias_c[n];
                if (EPI & 2) v = fmaxf(v, 0.f);
                if (EPI & 4) ((bf16*)Cv)[zC + row * (long)N + col] = (bf16)v;
                else         ((float*)Cv)[zC + row * (long)N + col] = v;
            }
        }
    }
}

// ---------------- fused flash attention with relevance bias, K-split ----------------
// Proven round-9 body (4 waves, 128-row Q-tile, single-buffered 2-barrier loop,
// 51 KB LDS, __expf softmax) + T1 bijective XCD chunking + T5 setprio.
// NOTE: exp2f experiment (round 10) REGRESSED (60->67 us, VALUBusy 34->41):
// libm exp2f carries range-fixup code; __expf lowers to v_mul+v_exp_f32. Keep __expf.
template<int SPLIT>
__launch_bounds__(256, 1)
__global__ void flash_attn(const bf16* __restrict__ qb, const bf16* __restrict__ kT,
                           const bf16* __restrict__ vT, const float* __restrict__ rq,
                           const float* __restrict__ rk, bf16* __restrict__ ctx,
                           float* __restrict__ opart, float* __restrict__ osum) {
    __shared__ __align__(16) bf16  Ksh[KT_ * HD_];   // [key][d], granule-swizzled
    __shared__ __align__(16) bf16  Vsh[HD_ * KT_];   // [d][key], granule-swizzled
    __shared__ __align__(16) float rks[4 * KT_];     // [r][key] fp32
    __shared__ __align__(16) bf16  Ps[4][32 * PSTR]; // per-wave P, 16B-aligned rows

    const int tid = threadIdx.x, wave = tid >> 6, lane = tid & 63;
    const int quad = lane >> 4, mr = lane & 15;
    const int nwg = 256 * SPLIT;
    const int lid = blockIdx.x + (blockIdx.y << 4) + (blockIdx.z << 8);
    const int wid = (lid & 7) * (nwg >> 3) + (lid >> 3);
    const int ksp = wid >> 8;
    const int pair = (wid >> 4) & 15, b = pair >> 3;
    const int bQ = (wid & 15) * 128;
    const long PB = (long)pair * L_ * HD_;
    const bf16* Qg = qb + PB;
    const bf16* Kg = kT + PB;
    const bf16* Vg = vT + PB;
    const float* rkb = rk + (long)b * L_ * 4;

    // Q fragments in registers (A-layout): rows bQ + wave*32 + f*16 + mr
    bf16x8 Qf[2][4], Qe[2];
#pragma unroll
    for (int f = 0; f < 2; f++) {
#pragma unroll
        for (int t = 0; t < 4; t++)
            Qf[f][t] = *(const bf16x8*)(Qg + (long)(bQ + wave * 32 + f * 16 + mr) * HD_ + t * 32 + quad * 8);
        bf16x8 z = {};
        if (quad == 0) {
            float4 v = *(const float4*)(rq + ((long)b * L_ + bQ + wave * 32 + f * 16 + mr) * 4);
            z[0] = (bf16)(v.x * RSCALE_); z[1] = (bf16)(v.y * RSCALE_);
            z[2] = (bf16)(v.z * RSCALE_); z[3] = (bf16)(v.w * RSCALE_);
        }
        Qe[f] = z;
    }

    bf16x8 ones;
#pragma unroll
    for (int j = 0; j < 8; j++) ones[j] = (bf16)1.0f;

    f32x4 O[2][8], Os[2];
#pragma unroll
    for (int f = 0; f < 2; f++) {
#pragma unroll
        for (int c = 0; c < 8; c++) { f32x4 z = {0.f, 0.f, 0.f, 0.f}; O[f][c] = z; }
        f32x4 z = {0.f, 0.f, 0.f, 0.f}; Os[f] = z;
    }

    const int tile0 = ksp * ((L_ / KT_) / SPLIT);
    const int tile1 = tile0 + (L_ / KT_) / SPLIT;
    for (int kt = tile0; kt < tile1; kt++) {
        const int kt0 = kt * KT_;
        // ---- stage K/V/rk (single buffer) ----
#pragma unroll
        for (int it = 0; it < 4; it++) {
            int G = it * 256 + tid;
            int r1 = G >> 4, g1 = (G & 15) ^ (r1 & 15);
            async16(Kg + (long)(kt0 + r1) * HD_ + g1 * 8, &Ksh[(it * 256 + wave * 64) * 8]);
            int r2 = G >> 3, g2 = (G & 7) ^ (r2 & 7);
            async16(Vg + (long)r2 * L_ + kt0 + g2 * 8, &Vsh[(it * 256 + wave * 64) * 8]);
        }
        if (tid < 64) {
            int r3 = tid >> 4, g3 = tid & 15;
            async16((const bf16*)(rkb + (long)r3 * L_ + kt0 + g3 * 4), (bf16*)&rks[0]);
        }
        __syncthreads();   // drains vmcnt -> LDS valid for all waves

        bf16* PsW = Ps[wave];

        // ---- S = Q K^T (+ ext bias chunk), 4 col-blocks of 16 keys ----
        f32x4 sc[4][2];
        __builtin_amdgcn_s_setprio(1);
#pragma unroll
        for (int c = 0; c < 4; c++) {
            f32x4 s0 = {0.f, 0.f, 0.f, 0.f}, s1 = s0;
#pragma unroll
            for (int t = 0; t < 4; t++) {
                bf16x8 kf = *(const bf16x8*)(Ksh + (c * 16 + mr) * HD_ + (((t * 4 + quad) ^ mr) * 8));
                s0 = MFMA(Qf[0][t], kf, s0);
                s1 = MFMA(Qf[1][t], kf, s1);
            }
            bf16x8 ke = {};
            if (quad == 0) {
                ke[0] = (bf16)rks[0 * KT_ + c * 16 + mr];
                ke[1] = (bf16)rks[1 * KT_ + c * 16 + mr];
                ke[2] = (bf16)rks[2 * KT_ + c * 16 + mr];
                ke[3] = (bf16)rks[3 * KT_ + c * 16 + mr];
            }
            s0 = MFMA(Qe[0], ke, s0);
            s1 = MFMA(Qe[1], ke, s1);
            sc[c][0] = s0; sc[c][1] = s1;
        }
        __builtin_amdgcn_s_setprio(0);

        // ---- P = exp(ALPHA*S) straight to LDS (no max, no shuffles) ----
#pragma unroll
        for (int f = 0; f < 2; f++) {
#pragma unroll
            for (int i = 0; i < 4; i++) {
                const int prow = (f * 16 + quad * 4 + i) * PSTR;
                PsW[prow + 0 * 16 + mr] = (bf16)__expf(sc[0][f][i] * ALPHA_);
                PsW[prow + 1 * 16 + mr] = (bf16)__expf(sc[1][f][i] * ALPHA_);
                PsW[prow + 2 * 16 + mr] = (bf16)__expf(sc[2][f][i] * ALPHA_);
                PsW[prow + 3 * 16 + mr] = (bf16)__expf(sc[3][f][i] * ALPHA_);
            }
        }

        // ---- O += P @ V ; Os += P @ ones (row sums) ----
        __builtin_amdgcn_s_setprio(1);
#pragma unroll
        for (int t = 0; t < 2; t++) {
            bf16x8 pf0 = *(const bf16x8*)(PsW + (0 * 16 + mr) * PSTR + t * 32 + quad * 8);
            bf16x8 pf1 = *(const bf16x8*)(PsW + (1 * 16 + mr) * PSTR + t * 32 + quad * 8);
            Os[0] = MFMA(pf0, ones, Os[0]);
            Os[1] = MFMA(pf1, ones, Os[1]);
#pragma unroll
            for (int c2 = 0; c2 < 8; c2++) {
                bf16x8 vf = *(const bf16x8*)(Vsh + (c2 * 16 + mr) * KT_ + (((t * 4 + quad) ^ (mr & 7)) * 8));
                O[0][c2] = MFMA(pf0, vf, O[0][c2]);
                O[1][c2] = MFMA(pf1, vf, O[1][c2]);
            }
        }
        __builtin_amdgcn_s_setprio(0);
        __syncthreads();   // all waves done reading K/V before restage
    }

    // ---- epilogue ----
    if (SPLIT == 1) {
        bf16* Cg = ctx + PB;
#pragma unroll
        for (int f = 0; f < 2; f++)
#pragma unroll
            for (int i = 0; i < 4; i++) {
                const float inv = 1.f / Os[f][i];
                const long row = bQ + wave * 32 + f * 16 + quad * 4 + i;
#pragma unroll
                for (int c2 = 0; c2 < 8; c2++)
                    Cg[row * HD_ + c2 * 16 + mr] = (bf16)(O[f][c2][i] * inv);
            }
    } else {
        float* Og = opart + (long)ksp * ((long)PAIRS_ * L_ * HD_) + PB;
        float* Sg = osum + (long)ksp * (PAIRS_ * L_) + pair * L_;
#pragma unroll
        for (int f = 0; f < 2; f++)
#pragma unroll
            for (int i = 0; i < 4; i++) {
                const long row = bQ + wave * 32 + f * 16 + quad * 4 + i;
#pragma unroll
                for (int c2 = 0; c2 < 8; c2++)
                    Og[row * HD_ + c2 * 16 + mr] = O[f][c2][i];
                if (mr == 0) Sg[row] = Os[f][i];
            }
    }
}

// --------- combine KS flash partials: ctx = (sum O_z) / (sum s_z) ----------
template<int KS>
__global__ void flash_reduce(const float* __restrict__ op, const float* __restrict__ os,
                             bf16* __restrict__ ctx) {
    const long PLHD = (long)PAIRS_ * L_ * HD_;
    long e = ((long)blockIdx.x * 256 + threadIdx.x) * 4;
    long row = e >> 7;                       // / HD_
    float4 a = *(const float4*)(op + e);
    float s = os[row];
#pragma unroll
    for (int z = 1; z < KS; z++) {
        float4 p = *(const float4*)(op + (long)z * PLHD + e);
        a.x += p.x; a.y += p.y; a.z += p.z; a.w += p.w;
        s += os[(long)z * PAIRS_ * L_ + row];
    }
    float inv = 1.f / s;
    bf16x4 o = {(bf16)(a.x * inv), (bf16)(a.y * inv),
                (bf16)(a.z * inv), (bf16)(a.w * inv)};
    *(bf16x4*)(ctx + e) = o;
}

// ---------------- LN1: layernorm(x1 + x2) * g + be ; fp32 + bf16 out ----------------
__global__ void layernorm_res(const float* __restrict__ x1, const float* __restrict__ x2,
                              const float* __restrict__ g, const float* __restrict__ be,
                              float* __restrict__ outf, bf16* __restrict__ outb) {
    const int row = blockIdx.x, tid = threadIdx.x;
    const long base = (long)row * D_ + tid * 4;
    float4 a = *(const float4*)(x1 + base);
    float4 b = *(const float4*)(x2 + base);
    float x[4] = {a.x + b.x, a.y + b.y, a.z + b.z, a.w + b.w};
    float s = x[0] + x[1] + x[2] + x[3];
    float s2 = x[0] * x[0] + x[1] * x[1] + x[2] * x[2] + x[3] * x[3];
#pragma unroll
    for (int off = 32; off; off >>= 1) { s += __shfl_xor(s, off, 64); s2 += __shfl_xor(s2, off, 64); }
    __shared__ float ps[4], ps2[4];
    int wave = tid >> 6, lane = tid & 63;
    if (lane == 0) { ps[wave] = s; ps2[wave] = s2; }
    __syncthreads();
    s  = ps[0] + ps[1] + ps[2] + ps[3];
    s2 = ps2[0] + ps2[1] + ps2[2] + ps2[3];
    float mean = s * (1.f / D_);
    float var  = s2 * (1.f / D_) - mean * mean;
    float rstd = rsqrtf(var + 1e-5f);
    float4 gg = *(const float4*)(g + tid * 4);
    float4 bb = *(const float4*)(be + tid * 4);
    float y0 = (x[0] - mean) * rstd * gg.x + bb.x;
    float y1 = (x[1] - mean) * rstd * gg.y + bb.y;
    float y2 = (x[2] - mean) * rstd * gg.z + bb.z;
    float y3 = (x[3] - mean) * rstd * gg.w + bb.w;
    float4 yo = {y0, y1, y2, y3};
    *(float4*)(outf + base) = yo;
    bf16x4 ob = {(bf16)y0, (bf16)y1, (bf16)y2, (bf16)y3};
    *(bf16x4*)(outb + base) = ob;
}

// ---------------- LN2: layernorm(sum_z parts[z] + b2 + h1) * g + be -> fp32 ----------
template<int SK>
__global__ void layernorm_res2(const float* __restrict__ parts, const float* __restrict__ b2,
                               const float* __restrict__ x2, const float* __restrict__ g,
                               const float* __restrict__ be, float* __restrict__ outf) {
    const int row = blockIdx.x, tid = threadIdx.x;
    const long base = (long)row * D_ + tid * 4;
    float4 a = *(const float4*)(parts + base);
#pragma unroll
    for (int z = 1; z < SK; z++) {
        float4 p = *(const float4*)(parts + (long)z * ROWS_ * D_ + base);
        a.x += p.x; a.y += p.y; a.z += p.z; a.w += p.w;
    }
    float4 bb2 = *(const float4*)(b2 + tid * 4);
    float4 b = *(const float4*)(x2 + base);
    float x[4] = {a.x + bb2.x + b.x, a.y + bb2.y + b.y, a.z + bb2.z + b.z, a.w + bb2.w + b.w};
    float s = x[0] + x[1] + x[2] + x[3];
    float s2 = x[0] * x[0] + x[1] * x[1] + x[2] * x[2] + x[3] * x[3];
#pragma unroll
    for (int off = 32; off; off >>= 1) { s += __shfl_xor(s, off, 64); s2 += __shfl_xor(s2, off, 64); }
    __shared__ float ps[4], ps2[4];
    int wave = tid >> 6, lane = tid & 63;
    if (lane == 0) { ps[wave] = s; ps2[wave] = s2; }
    __syncthreads();
    s  = ps[0] + ps[1] + ps[2] + ps[3];
    s2 = ps2[0] + ps2[1] + ps2[2] + ps2[3];
    float mean = s * (1.f / D_);
    float var  = s2 * (1.f / D_) - mean * mean;
    float rstd = rsqrtf(var + 1e-5f);
    float4 gg = *(const float4*)(g + tid * 4);
    float4 bb = *(const float4*)(be + tid * 4);
    float4 yo = {(x[0] - mean) * rstd * gg.x + bb.x, (x[1] - mean) * rstd * gg.y + bb.y,
                 (x[2] - mean) * rstd * gg.z + bb.z, (x[3] - mean) * rstd * gg.w + bb.w};
    *(float4*)(outf + base) = yo;
}

// ---------------- launch ----------------
extern "C" void kernel_launch(void* const* d_in, const int* in_sizes, int n_in,
                              void* d_out, int out_size, void* d_ws, size_t ws_size,
                              hipStream_t stream) {
    (void)in_sizes; (void)n_in; (void)out_size;
    const float* h   = (const float*)d_in[0];
    const float* rh  = (const float*)d_in[1];
    const float* Wq  = (const float*)d_in[2];
    const float* Wk  = (const float*)d_in[3];
    const float* Wv  = (const float*)d_in[4];
    const float* Wo  = (const float*)d_in[5];
    const float* Wrk = (const float*)d_in[6];
    const float* Wrq = (const float*)d_in[7];
    const float* W1  = (const float*)d_in[8];
    const float* b1  = (const float*)d_in[9];
    const float* W2  = (const float*)d_in[10];
    const float* b2  = (const float*)d_in[11];
    const float* g1  = (const float*)d_in[12];
    const float* be1 = (const float*)d_in[13];
    const float* g2  = (const float*)d_in[14];
    const float* be2 = (const float*)d_in[15];

    char* w = (char*)d_ws;
    size_t used = 0;
    auto alloc = [&](size_t bytes) { char* p = w + used; used += (bytes + 255) & ~(size_t)255; return p; };
    bf16*  hb   = (bf16*)alloc((size_t)ROWS_ * D_ * 2);       // 8 MB; later ctx, then h1b
    bf16*  Wqt  = (bf16*)alloc((size_t)D_ * D_ * 2);
    bf16*  Wkt  = (bf16*)alloc((size_t)D_ * D_ * 2);
    bf16*  Wvt  = (bf16*)alloc((size_t)D_ * D_ * 2);
    bf16*  Wot  = (bf16*)alloc((size_t)D_ * D_ * 2);
    bf16*  W1t  = (bf16*)alloc((size_t)D_ * FFN_ * 2);
    bf16*  W2t  = (bf16*)alloc((size_t)FFN_ * D_ * 2);
    bf16*  qb   = (bf16*)alloc((size_t)ROWS_ * D_ * 2);       // qb/kb/vb contiguous (z-batch out)
    bf16*  kb   = (bf16*)alloc((size_t)ROWS_ * D_ * 2);
    bf16*  vb   = (bf16*)alloc((size_t)ROWS_ * D_ * 2);
    bf16*  kT   = (bf16*)alloc((size_t)ROWS_ * D_ * 2);       // kT[m][d] = chunk[d*L+m]
    bf16*  vT   = (bf16*)alloc((size_t)ROWS_ * D_ * 2);       // vT[d][key]
    float* rq   = (float*)alloc((size_t)ROWS_ * 4 * 4);
    float* rk   = (float*)alloc((size_t)ROWS_ * 4 * 4);
    float* h1   = (float*)alloc((size_t)ROWS_ * D_ * 4);      // 16 MB, live to the end

    const size_t psz    = (size_t)ROWS_ * D_ * 4;             // 16 MB
    const size_t PLHD   = (size_t)PAIRS_ * L_ * HD_;          // elements
    const size_t needKS = 2 * PLHD * 4 + 2 * (size_t)PAIRS_ * L_ * 4;  // ~32.25 MB
    const size_t avail  = (ws_size > used) ? ws_size - used : 0;
    const int SK = (avail >= 4 * psz) ? 4 : (avail >= 2 * psz) ? 2 : 1;
    size_t region = (size_t)SK * psz;
    const int KS = (avail >= (needKS > region ? needKS : region)) ? 2 : 1;
    if (KS == 2 && needKS > region) region = needKS;
    float* P = (float*)alloc(region);
    float* hsa   = P;
    float* Opart = P;
    float* Osum  = P + 2 * PLHD;
    bf16* ctx = hb;
    bf16* mid = qb;    // 32 MB over qb..kT, live after flash
    bf16* h1b = hb;    // over hb, live after Wo

    const dim3 blk(256);
    const dim3 blk512(512);

    // 1. ALL preprocessing in one dispatch: cvt + 6 weight transposes + rqk
    prep_kernel<<<16400, blk, 0, stream>>>(h, hb, Wq, Wk, Wv, Wo, Wqt, Wkt, Wvt, Wot,
                                           W1, W1t, W2, W2t, rh, Wrq, Wrk, rq, rk);
    // 2. QKV projections, z=3 batched (192 blocks, 256^2 ring-4)
    gemm256<4><<<dim3(16, 4, 3), blk512, 0, stream>>>(hb, Wqt, qb, nullptr,
        ROWS_, D_, D_, D_, D_, 0, (long)D_ * D_, (long)ROWS_ * D_, 1.f);
    // 3. per-(b,n) K and V transposes in one dispatch
    transposeKV<<<8192, blk, 0, stream>>>(kb, kT, vb, vT);
    // 4. fused flash attention -> ctx (K-split 2 when workspace allows)
    if (KS == 2) {
        flash_attn<2><<<dim3(16, 16, 2), blk, 0, stream>>>(qb, kT, vT, rq, rk, ctx, Opart, Osum);
        flash_reduce<2><<<PAIRS_ * L_ * HD_ / 1024, blk, 0, stream>>>(Opart, Osum, ctx);
    } else {
        flash_attn<1><<<dim3(16, 16, 1), blk, 0, stream>>>(qb, kT, vT, rq, rk, ctx, Opart, Osum);
    }
    // 5. h_sa = ctx @ Wo (fp32)
    gemm128<64, 0><<<dim3(64, 8, 1), blk, 0, stream>>>(ctx, Wot, hsa, nullptr,
        ROWS_, D_, D_, D_, D_, 0, 0, 0, 1.f);
    // 6. h1 = LN(h_sa + h)
    layernorm_res<<<ROWS_, blk, 0, stream>>>(hsa, h, g1, be1, h1, h1b);
    // 7. mid = relu(h1 @ W1 + b1)  (256 blocks, 256^2 ring-4)
    gemm256<7><<<dim3(16, 16, 1), blk512, 0, stream>>>(h1b, W1t, mid, b1,
        ROWS_, FFN_, D_, D_, D_, 0, 0, 0, 1.f);
    // 8-9. hf partials ; out = LN(h1 + sum + b2)
    {
        const int KC = FFN_ / SK;
        if (SK == 4) {
            gemm256<0><<<dim3(16, 4, 4), blk512, 0, stream>>>(mid, W2t, P, nullptr,
                ROWS_, D_, KC, FFN_, FFN_, KC, KC, (long)ROWS_ * D_, 1.f);
            layernorm_res2<4><<<ROWS_, blk, 0, stream>>>(P, b2, h1, g2, be2, (float*)d_out);
        } else if (SK == 2) {
            gemm256<0><<<dim3(16, 4, 2), blk512, 0, stream>>>(mid, W2t, P, nullptr,
                ROWS_, D_, KC, FFN_, FFN_, KC, KC, (long)ROWS_ * D_, 1.f);
            layernorm_res2<2><<<ROWS_, blk, 0, stream>>>(P, b2, h1, g2, be2, (float*)d_out);
        } else {
            gemm128<128, 0><<<dim3(32, 8, 1), blk, 0, stream>>>(mid, W2t, P, nullptr,
                ROWS_, D_, FFN_, FFN_, FFN_, 0, 0, 0, 1.f);
            layernorm_res2<1><<<ROWS_, blk, 0, stream>>>(P, b2, h1, g2, be2, (float*)d_out);
        }
    }
}